// Round 5
// baseline (530.602 us; speedup 1.0000x reference)
//
#include <hip/hip_runtime.h>
#include <hip/hip_bf16.h>

// ---------------------------------------------------------------------------
// BasicTransformerBlock (l2-attention x2 + GEGLU FFN), MI355X gfx950
// Round 5: attention restructured — S^T compute (A=Qj, B=Qi regs), V^T
// materialized by the projection GEMM, i=32 rows/wave (2 tiles), packed
// b64 P-writes, barrier-free wave-local P. GEMMs unchanged (m97-style).
// ---------------------------------------------------------------------------

typedef short bf16x8 __attribute__((ext_vector_type(8)));
typedef float f32x4 __attribute__((ext_vector_type(4)));
typedef unsigned short u16;
typedef unsigned int u32;

__device__ __forceinline__ float bf2f(u16 u) {
    return __uint_as_float(((u32)u) << 16);
}
__device__ __forceinline__ u16 f2bf(float f) {
    u32 u = __float_as_uint(f);
    u32 rb = ((u >> 16) & 1u) + 0x7fffu;   // round-to-nearest-even
    return (u16)((u + rb) >> 16);
}
__device__ __forceinline__ float gelu_exact(float x) {
    return 0.5f * x * (1.f + erff(x * 0.7071067811865475f));
}
__device__ __forceinline__ void gl2lds16(const u16* g, u16* l) {
    __builtin_amdgcn_global_load_lds(
        (const __attribute__((address_space(1))) void*)(unsigned long long)(uintptr_t)g,
        (__attribute__((address_space(3))) void*)(unsigned long long)(uintptr_t)l,
        16, 0, 0);
}

// ---------------------------------------------------------------------------
// fp32 [R][C] -> bf16 [C][R] transpose (weight prep)
__global__ __launch_bounds__(256) void transpose_f32_bf16(const float* __restrict__ in,
                                                          u16* __restrict__ out,
                                                          int R, int C) {
    __shared__ float tile[32][33];
    int bx = blockIdx.x, by = blockIdx.y;
    int t = threadIdx.x;
    int c = t & 31, r0 = (t >> 5) * 4;
#pragma unroll
    for (int i = 0; i < 4; i++)
        tile[r0 + i][c] = in[(size_t)(by * 32 + r0 + i) * C + bx * 32 + c];
    __syncthreads();
#pragma unroll
    for (int i = 0; i < 4; i++)
        out[(size_t)(bx * 32 + r0 + i) * R + by * 32 + c] = f2bf(tile[c][r0 + i]);
}

// ---------------------------------------------------------------------------
// LayerNorm: x fp32 [rows][512] -> out bf16, one block per row
__global__ __launch_bounds__(256) void ln_kernel(const float* __restrict__ x,
                                                 const float* __restrict__ w,
                                                 const float* __restrict__ b,
                                                 u16* __restrict__ out) {
    int row = blockIdx.x, t = threadIdx.x;
    const float* xr = x + (size_t)row * 512;
    float2 v = *(const float2*)(xr + t * 2);
    float s1 = v.x + v.y;
    float s2 = v.x * v.x + v.y * v.y;
#pragma unroll
    for (int m = 1; m < 64; m <<= 1) {
        s1 += __shfl_xor(s1, m);
        s2 += __shfl_xor(s2, m);
    }
    __shared__ float r1[4], r2[4];
    int wave = t >> 6, lane = t & 63;
    if (lane == 0) { r1[wave] = s1; r2[wave] = s2; }
    __syncthreads();
    float tot1 = r1[0] + r1[1] + r1[2] + r1[3];
    float tot2 = r2[0] + r2[1] + r2[2] + r2[3];
    float mu = tot1 * (1.f / 512.f);
    float var = tot2 * (1.f / 512.f) - mu * mu;
    float rs = rsqrtf(var + 1e-5f);
    float2 wv = *(const float2*)(w + t * 2);
    float2 bv = *(const float2*)(b + t * 2);
    float o0 = (v.x - mu) * rs * wv.x + bv.x;
    float o1 = (v.y - mu) * rs * wv.y + bv.y;
    u32 pack = (u32)f2bf(o0) | ((u32)f2bf(o1) << 16);
    *(u32*)(out + (size_t)row * 512 + t * 2) = pack;
}

// ---------------------------------------------------------------------------
// m97-style MFMA GEMM: C[M,N] = A[M,K](bf16) * BT[N,K]^T(bf16) + bias(fp32)
// 128x128 tile, 4 waves (each 64x64), global_load_lds 16B staging.
// MODE 1: bf16 out | 2: fp32 out = acc + res | 4: qv split:
//   cols<512 (q): outb = qbuf [(b*8+h)][n][64]
//   cols>=512 (v): outb2 = vtbuf [(b*8+h)][64][2048] (transposed, packed 8B)
template <int MODE>
__global__ __launch_bounds__(256) void gemm128(const u16* __restrict__ A,
                                               const u16* __restrict__ BT,
                                               const float* __restrict__ bias,
                                               const float* __restrict__ bias2,
                                               const float* __restrict__ res,
                                               float* __restrict__ outf,
                                               u16* __restrict__ outb,
                                               u16* __restrict__ outb2,
                                               int M, int N, int K) {
    __shared__ u16 As[128 * 32];
    __shared__ u16 Bs[128 * 32];
    int t = threadIdx.x;
    int wave = t >> 6, lane = t & 63, quad = lane >> 4, l16 = lane & 15;
    int m0 = blockIdx.x * 128, n0 = blockIdx.y * 128;
    int wm = (wave >> 1) * 64, wn = (wave & 1) * 64;
    f32x4 acc[4][4];
#pragma unroll
    for (int i = 0; i < 4; i++)
#pragma unroll
        for (int j = 0; j < 4; j++) acc[i][j] = (f32x4){0.f, 0.f, 0.f, 0.f};
    const u16* Ag = A + (size_t)(m0 + wave * 32 + (lane >> 2)) * K + (lane & 3) * 8;
    const u16* Bg = BT + (size_t)(n0 + wave * 32 + (lane >> 2)) * K + (lane & 3) * 8;
    u16* Al = As + wave * 32 * 32;
    u16* Bl = Bs + wave * 32 * 32;
    const size_t rstep = (size_t)16 * K;
    for (int k0 = 0; k0 < K; k0 += 32) {
        __syncthreads();
        gl2lds16(Ag + k0, Al);
        gl2lds16(Ag + k0 + rstep, Al + 16 * 32);
        gl2lds16(Bg + k0, Bl);
        gl2lds16(Bg + k0 + rstep, Bl + 16 * 32);
        asm volatile("s_waitcnt vmcnt(0)" ::: "memory");
        __syncthreads();
        bf16x8 a[4], b[4];
#pragma unroll
        for (int i = 0; i < 4; i++) {
            a[i] = *(const bf16x8*)&As[(wm + i * 16 + l16) * 32 + quad * 8];
            b[i] = *(const bf16x8*)&Bs[(wn + i * 16 + l16) * 32 + quad * 8];
        }
#pragma unroll
        for (int i = 0; i < 4; i++)
#pragma unroll
            for (int j = 0; j < 4; j++)
                acc[i][j] = __builtin_amdgcn_mfma_f32_16x16x32_bf16(a[i], b[j], acc[i][j], 0, 0, 0);
    }
    int row_base = m0 + wm + quad * 4;
    int col_base = n0 + wn + l16;
#pragma unroll
    for (int j = 0; j < 4; j++) {
        int col = col_base + j * 16;
        float bv;
        if (MODE == 4) bv = (col < 512) ? bias[col] : bias2[col - 512];
        else bv = bias[col];
#pragma unroll
        for (int i = 0; i < 4; i++) {
            int rowA = row_base + i * 16;
            if (MODE == 4) {
                if (col < 512) {
                    int hh = col >> 6, d = col & 63;
#pragma unroll
                    for (int r = 0; r < 4; r++) {
                        int row = rowA + r;
                        outb[((size_t)((row >> 11) * 8 + hh) * 2048 + (row & 2047)) * 64 + d] =
                            f2bf(acc[i][j][r] + bv);
                    }
                } else {
                    int c2 = col - 512;
                    int hh = c2 >> 6, d = c2 & 63;
                    u32 lo = (u32)f2bf(acc[i][j][0] + bv) | ((u32)f2bf(acc[i][j][1] + bv) << 16);
                    u32 hi = (u32)f2bf(acc[i][j][2] + bv) | ((u32)f2bf(acc[i][j][3] + bv) << 16);
                    uint2 pk; pk.x = lo; pk.y = hi;
                    *(uint2*)&outb2[((size_t)((rowA >> 11) * 8 + hh) * 64 + d) * 2048 + (rowA & 2047)] = pk;
                }
            } else {
#pragma unroll
                for (int r = 0; r < 4; r++) {
                    int row = rowA + r;
                    float val = acc[i][j][r] + bv;
                    if (MODE == 1) {
                        outb[(size_t)row * N + col] = f2bf(val);
                    } else {
                        size_t idx = (size_t)row * N + col;
                        outf[idx] = val + res[idx];
                    }
                }
            }
        }
    }
}

// ---------------------------------------------------------------------------
// AA[tok] = 0.125 * sum_d q[tok][d]^2, q = qbuf [32*2048][64] bf16
__global__ __launch_bounds__(256) void aa_kernel(const u16* __restrict__ q,
                                                 float* __restrict__ aa) {
    int t = threadIdx.x;
    int tok = blockIdx.x * 32 + (t >> 3);
    int l8 = t & 7;
    const u16* row = q + (size_t)tok * 64 + l8 * 8;
    uint4 u = *(const uint4*)row;
    u32 c[4] = {u.x, u.y, u.z, u.w};
    float s = 0.f;
#pragma unroll
    for (int k = 0; k < 4; k++) {
        float a = bf2f((u16)(c[k] & 0xffff));
        float b = bf2f((u16)(c[k] >> 16));
        s += a * a + b * b;
    }
    s += __shfl_xor(s, 1); s += __shfl_xor(s, 2); s += __shfl_xor(s, 4);
    if (l8 == 0) aa[tok] = s * 0.125f;
}

// ---------------------------------------------------------------------------
// MFMA flash L2-attention, S^T formulation, static max (=0 since K=Q).
// qbuf [bh][2048][64]; vtbuf [bh][64][2048]; aas prescaled 0.125*||q||^2.
// Block (itile of 128 rows, bh), 4 waves; wave w owns i-rows w*32..+31.
// p = exp(0.25*S - aa_j - aa_i); P is wave-local (no barrier).
__global__ __launch_bounds__(256) void attn_mfma(const u16* __restrict__ qbuf,
                                                 const u16* __restrict__ vtbuf,
                                                 const float* __restrict__ aas,
                                                 u16* __restrict__ out) {
    __shared__ u16 Qj[64][72];      // j-token rows [j][d]
    __shared__ u16 VT[64][72];      // V^T rows [d][j]
    __shared__ u16 Pl[4][32][72];   // per-wave P [i-local][j]
    int itile = blockIdx.x, bh = blockIdx.y;
    const u16* qb = qbuf + (size_t)bh * 2048 * 64;
    const u16* vtb = vtbuf + (size_t)bh * 64 * 2048;
    const float* aab = aas + (size_t)bh * 2048;
    int t = threadIdx.x;
    int wave = t >> 6, lane = t & 63, quad = lane >> 4, l16 = lane & 15;
    int ibase = itile * 128 + wave * 32;
    // Qi B-fragments (held in registers): B[n=i][k=d]
    bf16x8 qf[2][2];
    float ci[2];
#pragma unroll
    for (int tt = 0; tt < 2; tt++) {
        int ir = ibase + tt * 16 + l16;
        qf[tt][0] = *(const bf16x8*)(qb + (size_t)ir * 64 + quad * 8);
        qf[tt][1] = *(const bf16x8*)(qb + (size_t)ir * 64 + 32 + quad * 8);
        ci[tt] = aab[ir];
    }
    f32x4 O[2][4];
#pragma unroll
    for (int tt = 0; tt < 2; tt++)
#pragma unroll
        for (int nt = 0; nt < 4; nt++) O[tt][nt] = (f32x4){0.f, 0.f, 0.f, 0.f};
    float lr[2] = {0.f, 0.f};
    int sr = t >> 2, sc = (t & 3) * 16;

    for (int j0 = 0; j0 < 2048; j0 += 64) {
        __syncthreads();   // previous iteration's Qj/VT reads complete
        {   // stage Qj rows [j][d] and VT rows [d][j] — both straight copies
            const u16* srcq = qb + (size_t)(j0 + sr) * 64 + sc;
            uint4 qa = *(const uint4*)srcq;
            uint4 qc = *(const uint4*)(srcq + 8);
            const u16* srcv = vtb + (size_t)sr * 2048 + j0 + sc;
            uint4 va = *(const uint4*)srcv;
            uint4 vc = *(const uint4*)(srcv + 8);
            *(uint4*)&Qj[sr][sc] = qa;
            *(uint4*)&Qj[sr][sc + 8] = qc;
            *(uint4*)&VT[sr][sc] = va;
            *(uint4*)&VT[sr][sc + 8] = vc;
        }
        __syncthreads();
        // ---- S^T = Qj . Qi^T : C[m=j][n=i] ----
        f32x4 sa[4][2];
#pragma unroll
        for (int jt = 0; jt < 4; jt++) {
            bf16x8 aj0 = *(const bf16x8*)&Qj[jt * 16 + l16][quad * 8];
            bf16x8 aj1 = *(const bf16x8*)&Qj[jt * 16 + l16][32 + quad * 8];
#pragma unroll
            for (int tt = 0; tt < 2; tt++) {
                f32x4 z = {0.f, 0.f, 0.f, 0.f};
                z = __builtin_amdgcn_mfma_f32_16x16x32_bf16(aj0, qf[tt][0], z, 0, 0, 0);
                z = __builtin_amdgcn_mfma_f32_16x16x32_bf16(aj1, qf[tt][1], z, 0, 0, 0);
                sa[jt][tt] = z;
            }
        }
        // ---- p = exp(0.25*S - aa_j - aa_i); pack b64 into Pl ----
#pragma unroll
        for (int jt = 0; jt < 4; jt++) {
            float4 aav = *(const float4*)(aab + j0 + jt * 16 + quad * 4);
#pragma unroll
            for (int tt = 0; tt < 2; tt++) {
                float p0 = __expf(sa[jt][tt][0] * 0.25f - aav.x - ci[tt]);
                float p1 = __expf(sa[jt][tt][1] * 0.25f - aav.y - ci[tt]);
                float p2 = __expf(sa[jt][tt][2] * 0.25f - aav.z - ci[tt]);
                float p3 = __expf(sa[jt][tt][3] * 0.25f - aav.w - ci[tt]);
                lr[tt] += p0 + p1 + p2 + p3;
                uint2 pk;
                pk.x = (u32)f2bf(p0) | ((u32)f2bf(p1) << 16);
                pk.y = (u32)f2bf(p2) | ((u32)f2bf(p3) << 16);
                *(uint2*)&Pl[wave][tt * 16 + l16][jt * 16 + quad * 4] = pk;
            }
        }
        // ---- O += P @ V : A = Pl rows (wave-local), B = VT rows ----
#pragma unroll
        for (int c = 0; c < 2; c++) {
            bf16x8 pa[2];
#pragma unroll
            for (int tt = 0; tt < 2; tt++)
                pa[tt] = *(const bf16x8*)&Pl[wave][tt * 16 + l16][c * 32 + quad * 8];
#pragma unroll
            for (int nt = 0; nt < 4; nt++) {
                bf16x8 vf = *(const bf16x8*)&VT[nt * 16 + l16][c * 32 + quad * 8];
#pragma unroll
                for (int tt = 0; tt < 2; tt++)
                    O[tt][nt] = __builtin_amdgcn_mfma_f32_16x16x32_bf16(pa[tt], vf, O[tt][nt], 0, 0, 0);
            }
        }
    }
    // epilogue: out [8192][512] bf16
    int b = bh >> 3, h = bh & 7;
#pragma unroll
    for (int tt = 0; tt < 2; tt++) {
        float s = lr[tt];
        s += __shfl_xor(s, 16);
        s += __shfl_xor(s, 32);
        float inv = 1.f / s;   // valid at lane l16 for row i=l16 of tile tt
#pragma unroll
        for (int r = 0; r < 4; r++) {
            float invr = __shfl(inv, quad * 4 + r);   // row i = quad*4+r
            size_t row = (size_t)(b * 2048 + ibase + tt * 16 + quad * 4 + r);
            u16* o = out + row * 512 + h * 64 + l16;
            o[0]  = f2bf(O[tt][0][r] * invr);
            o[16] = f2bf(O[tt][1][r] * invr);
            o[32] = f2bf(O[tt][2][r] * invr);
            o[48] = f2bf(O[tt][3][r] * invr);
        }
    }
}

// ---------------------------------------------------------------------------
// GEGLU: g[m,c] = h[m,c] * gelu(h[m,2048+c]),  h [8192][4096] bf16
__global__ __launch_bounds__(256) void geglu_kernel(const u16* __restrict__ h,
                                                    u16* __restrict__ g) {
    size_t i = ((size_t)blockIdx.x * 256 + threadIdx.x) * 4;
    size_t m = i >> 11;
    int c = (int)(i & 2047);
    const u16* p = h + m * 4096 + c;
    uint2 ua = *(const uint2*)p;
    uint2 ug = *(const uint2*)(p + 2048);
    float a0 = bf2f((u16)(ua.x & 0xffff)), a1 = bf2f((u16)(ua.x >> 16));
    float a2 = bf2f((u16)(ua.y & 0xffff)), a3 = bf2f((u16)(ua.y >> 16));
    float g0 = bf2f((u16)(ug.x & 0xffff)), g1 = bf2f((u16)(ug.x >> 16));
    float g2 = bf2f((u16)(ug.y & 0xffff)), g3 = bf2f((u16)(ug.y >> 16));
    float r0 = a0 * gelu_exact(g0);
    float r1 = a1 * gelu_exact(g1);
    float r2 = a2 * gelu_exact(g2);
    float r3 = a3 * gelu_exact(g3);
    uint2 o;
    o.x = (u32)f2bf(r0) | ((u32)f2bf(r1) << 16);
    o.y = (u32)f2bf(r2) | ((u32)f2bf(r3) << 16);
    *(uint2*)(g + m * 2048 + c) = o;
}

// ---------------------------------------------------------------------------
extern "C" void kernel_launch(void* const* d_in, const int* in_sizes, int n_in,
                              void* d_out, int out_size, void* d_ws, size_t ws_size,
                              hipStream_t stream) {
    const float* x      = (const float*)d_in[0];
    const float* sa_w   = (const float*)d_in[1];
    const float* sa_b   = (const float*)d_in[2];
    const float* ca_w   = (const float*)d_in[3];
    const float* ca_b   = (const float*)d_in[4];
    const float* ffn_w  = (const float*)d_in[5];
    const float* ffn_b  = (const float*)d_in[6];
    const float* a1_wq  = (const float*)d_in[7];
    const float* a1_bq  = (const float*)d_in[8];
    const float* a1_wv  = (const float*)d_in[9];
    const float* a1_bv  = (const float*)d_in[10];
    const float* a1_wo  = (const float*)d_in[11];
    const float* a1_bo  = (const float*)d_in[12];
    const float* a2_wq  = (const float*)d_in[13];
    const float* a2_bq  = (const float*)d_in[14];
    const float* a2_wv  = (const float*)d_in[15];
    const float* a2_bv  = (const float*)d_in[16];
    const float* a2_wo  = (const float*)d_in[17];
    const float* a2_bo  = (const float*)d_in[18];
    const float* ff_w1  = (const float*)d_in[19];
    const float* ff_b1  = (const float*)d_in[20];
    const float* ff_w2  = (const float*)d_in[21];
    const float* ff_b2  = (const float*)d_in[22];

    char* ws = (char*)d_ws;
    const size_t MB = 1ull << 20;
    float* x_res   = (float*)(ws);              // 16 MB fp32 residual stream
    u16* xn        = (u16*)(ws + 16 * MB);      // 8 MB normed activations (bf16)
    u16* wT_a1qv   = (u16*)(ws + 24 * MB);      // 1 MB [1024][512] (wq^T | wv^T)
    u16* wT_a2qv   = (u16*)(ws + 25 * MB);      // 1 MB
    u16* wT_a1o    = (u16*)(ws + 26 * MB);      // 0.5 MB
    u16* wT_a2o    = (u16*)(ws + 26 * MB + 512 * 1024);
    u16* wT_ff1    = (u16*)(ws + 27 * MB);      // 4 MB [4096][512]
    u16* wT_ff2    = (u16*)(ws + 31 * MB);      // 2 MB [512][2048]
    // attn-phase buffers (overlap with ffn-phase hbuf)
    u16* qbuf      = (u16*)(ws + 34 * MB);      // 8 MB [bh][2048][64]
    u16* vtbuf     = (u16*)(ws + 42 * MB);      // 8 MB [bh][64][2048]
    float* aab     = (float*)(ws + 50 * MB);    // 256 KB (0.125*||q||^2)
    u16* attn_o    = (u16*)(ws + 51 * MB);      // 8 MB bf16 [8192][512]
    // ffn-phase buffers
    u16* hbuf      = (u16*)(ws + 34 * MB);      // 64 MB [8192][4096] bf16
    u16* gbuf      = (u16*)(ws + 98 * MB);      // 32 MB [8192][2048] bf16

    (void)in_sizes; (void)n_in; (void)out_size; (void)ws_size;

    // weight transposes (fp32 -> bf16 [N][K]); q|v concatenated
    transpose_f32_bf16<<<dim3(16, 16), 256, 0, stream>>>(a1_wq, wT_a1qv, 512, 512);
    transpose_f32_bf16<<<dim3(16, 16), 256, 0, stream>>>(a1_wv, wT_a1qv + 512 * 512, 512, 512);
    transpose_f32_bf16<<<dim3(16, 16), 256, 0, stream>>>(a2_wq, wT_a2qv, 512, 512);
    transpose_f32_bf16<<<dim3(16, 16), 256, 0, stream>>>(a2_wv, wT_a2qv + 512 * 512, 512, 512);
    transpose_f32_bf16<<<dim3(16, 16), 256, 0, stream>>>(a1_wo, wT_a1o, 512, 512);
    transpose_f32_bf16<<<dim3(16, 16), 256, 0, stream>>>(a2_wo, wT_a2o, 512, 512);
    transpose_f32_bf16<<<dim3(128, 16), 256, 0, stream>>>(ff_w1, wT_ff1, 512, 4096);
    transpose_f32_bf16<<<dim3(16, 64), 256, 0, stream>>>(ff_w2, wT_ff2, 2048, 512);

    // === attention 1 (self) ===
    ln_kernel<<<8192, 256, 0, stream>>>(x, sa_w, sa_b, xn);
    gemm128<4><<<dim3(64, 8), 256, 0, stream>>>(xn, wT_a1qv, a1_bq, a1_bv, nullptr, nullptr, qbuf, vtbuf, 8192, 1024, 512);
    aa_kernel<<<2048, 256, 0, stream>>>(qbuf, aab);
    attn_mfma<<<dim3(16, 32), 256, 0, stream>>>(qbuf, vtbuf, aab, attn_o);
    gemm128<2><<<dim3(64, 4), 256, 0, stream>>>(attn_o, wT_a1o, a1_bo, nullptr, x, x_res, nullptr, nullptr, 8192, 512, 512);

    // === attention 2 ("cross", k=q, v from x) ===
    ln_kernel<<<8192, 256, 0, stream>>>(x_res, ca_w, ca_b, xn);
    gemm128<4><<<dim3(64, 8), 256, 0, stream>>>(xn, wT_a2qv, a2_bq, a2_bv, nullptr, nullptr, qbuf, vtbuf, 8192, 1024, 512);
    aa_kernel<<<2048, 256, 0, stream>>>(qbuf, aab);
    attn_mfma<<<dim3(16, 32), 256, 0, stream>>>(qbuf, vtbuf, aab, attn_o);
    gemm128<2><<<dim3(64, 4), 256, 0, stream>>>(attn_o, wT_a2o, a2_bo, nullptr, x_res, x_res, nullptr, nullptr, 8192, 512, 512);

    // === GEGLU FFN ===
    ln_kernel<<<8192, 256, 0, stream>>>(x_res, ffn_w, ffn_b, xn);
    gemm128<1><<<dim3(64, 32), 256, 0, stream>>>(xn, wT_ff1, ff_b1, nullptr, nullptr, nullptr, hbuf, nullptr, 8192, 4096, 512);
    geglu_kernel<<<16384, 256, 0, stream>>>(hbuf, gbuf);
    gemm128<2><<<dim3(64, 4), 256, 0, stream>>>(gbuf, wT_ff2, ff_b2, nullptr, x_res, (float*)d_out, nullptr, nullptr, 8192, 512, 2048);
}

// Round 6
// 487.567 us; speedup vs baseline: 1.0883x; 1.0883x over previous
//
#include <hip/hip_runtime.h>
#include <hip/hip_bf16.h>

// ---------------------------------------------------------------------------
// BasicTransformerBlock (l2-attention x2 + GEGLU FFN), MI355X gfx950
// Round 6: attn = S^T structure at round-4 parallelism (16 rows/wave, 1024
// blocks); GEMM = double-buffered K-loop with raw s_barrier + vmcnt(4) so
// prefetch stays in flight across the barrier (critical at 1-2 blocks/CU).
// ---------------------------------------------------------------------------

typedef short bf16x8 __attribute__((ext_vector_type(8)));
typedef float f32x4 __attribute__((ext_vector_type(4)));
typedef unsigned short u16;
typedef unsigned int u32;

__device__ __forceinline__ float bf2f(u16 u) {
    return __uint_as_float(((u32)u) << 16);
}
__device__ __forceinline__ u16 f2bf(float f) {
    u32 u = __float_as_uint(f);
    u32 rb = ((u >> 16) & 1u) + 0x7fffu;   // round-to-nearest-even
    return (u16)((u + rb) >> 16);
}
__device__ __forceinline__ float gelu_exact(float x) {
    return 0.5f * x * (1.f + erff(x * 0.7071067811865475f));
}
__device__ __forceinline__ void gl2lds16(const u16* g, u16* l) {
    __builtin_amdgcn_global_load_lds(
        (const __attribute__((address_space(1))) void*)(unsigned long long)(uintptr_t)g,
        (__attribute__((address_space(3))) void*)(unsigned long long)(uintptr_t)l,
        16, 0, 0);
}

// ---------------------------------------------------------------------------
// fp32 [R][C] -> bf16 [C][R] transpose (weight prep)
__global__ __launch_bounds__(256) void transpose_f32_bf16(const float* __restrict__ in,
                                                          u16* __restrict__ out,
                                                          int R, int C) {
    __shared__ float tile[32][33];
    int bx = blockIdx.x, by = blockIdx.y;
    int t = threadIdx.x;
    int c = t & 31, r0 = (t >> 5) * 4;
#pragma unroll
    for (int i = 0; i < 4; i++)
        tile[r0 + i][c] = in[(size_t)(by * 32 + r0 + i) * C + bx * 32 + c];
    __syncthreads();
#pragma unroll
    for (int i = 0; i < 4; i++)
        out[(size_t)(bx * 32 + r0 + i) * R + by * 32 + c] = f2bf(tile[c][r0 + i]);
}

// ---------------------------------------------------------------------------
// LayerNorm: x fp32 [rows][512] -> out bf16, one block per row
__global__ __launch_bounds__(256) void ln_kernel(const float* __restrict__ x,
                                                 const float* __restrict__ w,
                                                 const float* __restrict__ b,
                                                 u16* __restrict__ out) {
    int row = blockIdx.x, t = threadIdx.x;
    const float* xr = x + (size_t)row * 512;
    float2 v = *(const float2*)(xr + t * 2);
    float s1 = v.x + v.y;
    float s2 = v.x * v.x + v.y * v.y;
#pragma unroll
    for (int m = 1; m < 64; m <<= 1) {
        s1 += __shfl_xor(s1, m);
        s2 += __shfl_xor(s2, m);
    }
    __shared__ float r1[4], r2[4];
    int wave = t >> 6, lane = t & 63;
    if (lane == 0) { r1[wave] = s1; r2[wave] = s2; }
    __syncthreads();
    float tot1 = r1[0] + r1[1] + r1[2] + r1[3];
    float tot2 = r2[0] + r2[1] + r2[2] + r2[3];
    float mu = tot1 * (1.f / 512.f);
    float var = tot2 * (1.f / 512.f) - mu * mu;
    float rs = rsqrtf(var + 1e-5f);
    float2 wv = *(const float2*)(w + t * 2);
    float2 bv = *(const float2*)(b + t * 2);
    float o0 = (v.x - mu) * rs * wv.x + bv.x;
    float o1 = (v.y - mu) * rs * wv.y + bv.y;
    u32 pack = (u32)f2bf(o0) | ((u32)f2bf(o1) << 16);
    *(u32*)(out + (size_t)row * 512 + t * 2) = pack;
}

// ---------------------------------------------------------------------------
// MFMA GEMM, 128x128 tile, DOUBLE-BUFFERED K-loop: prefetch tile k+1 while
// computing tile k; raw barriers keep prefetch in flight (vmcnt(4), never 0).
// MODE 1: bf16 out | 2: fp32 out = acc + res | 4: qv split (q rows / v^T)
template <int MODE>
__global__ __launch_bounds__(256) void gemm128(const u16* __restrict__ A,
                                               const u16* __restrict__ BT,
                                               const float* __restrict__ bias,
                                               const float* __restrict__ bias2,
                                               const float* __restrict__ res,
                                               float* __restrict__ outf,
                                               u16* __restrict__ outb,
                                               u16* __restrict__ outb2,
                                               int M, int N, int K) {
    __shared__ u16 As[2][128 * 32];
    __shared__ u16 Bs[2][128 * 32];
    int t = threadIdx.x;
    int wave = t >> 6, lane = t & 63, quad = lane >> 4, l16 = lane & 15;
    int m0 = blockIdx.x * 128, n0 = blockIdx.y * 128;
    int wm = (wave >> 1) * 64, wn = (wave & 1) * 64;
    f32x4 acc[4][4];
#pragma unroll
    for (int i = 0; i < 4; i++)
#pragma unroll
        for (int j = 0; j < 4; j++) acc[i][j] = (f32x4){0.f, 0.f, 0.f, 0.f};
    const u16* Ag = A + (size_t)(m0 + wave * 32 + (lane >> 2)) * K + (lane & 3) * 8;
    const u16* Bg = BT + (size_t)(n0 + wave * 32 + (lane >> 2)) * K + (lane & 3) * 8;
    int lo = wave * 32 * 32;
    const size_t rstep = (size_t)16 * K;
    // prologue: tile 0 -> buffer 0
    gl2lds16(Ag, &As[0][lo]);
    gl2lds16(Ag + rstep, &As[0][lo + 16 * 32]);
    gl2lds16(Bg, &Bs[0][lo]);
    gl2lds16(Bg + rstep, &Bs[0][lo + 16 * 32]);
    int buf = 0;
    for (int k0 = 0; k0 < K; k0 += 32, buf ^= 1) {
        int kn = (k0 + 32 < K) ? (k0 + 32) : k0;   // last iter: dummy re-load
        int nb = buf ^ 1;
        // all waves done READING buffer nb (prefetch target) from 2 iters ago
        asm volatile("s_waitcnt lgkmcnt(0)\n\ts_barrier" ::: "memory");
        gl2lds16(Ag + kn, &As[nb][lo]);
        gl2lds16(Ag + kn + rstep, &As[nb][lo + 16 * 32]);
        gl2lds16(Bg + kn, &Bs[nb][lo]);
        gl2lds16(Bg + kn + rstep, &Bs[nb][lo + 16 * 32]);
        // wait current buffer's 4 loads (issued last iter) -- NOT the new 4
        asm volatile("s_waitcnt vmcnt(4)\n\ts_barrier" ::: "memory");
        bf16x8 a[4], b[4];
#pragma unroll
        for (int i = 0; i < 4; i++) {
            a[i] = *(const bf16x8*)&As[buf][(wm + i * 16 + l16) * 32 + quad * 8];
            b[i] = *(const bf16x8*)&Bs[buf][(wn + i * 16 + l16) * 32 + quad * 8];
        }
#pragma unroll
        for (int i = 0; i < 4; i++)
#pragma unroll
            for (int j = 0; j < 4; j++)
                acc[i][j] = __builtin_amdgcn_mfma_f32_16x16x32_bf16(a[i], b[j], acc[i][j], 0, 0, 0);
    }
    int row_base = m0 + wm + quad * 4;
    int col_base = n0 + wn + l16;
#pragma unroll
    for (int j = 0; j < 4; j++) {
        int col = col_base + j * 16;
        float bv;
        if (MODE == 4) bv = (col < 512) ? bias[col] : bias2[col - 512];
        else bv = bias[col];
#pragma unroll
        for (int i = 0; i < 4; i++) {
            int rowA = row_base + i * 16;
            if (MODE == 4) {
                if (col < 512) {
                    int hh = col >> 6, d = col & 63;
#pragma unroll
                    for (int r = 0; r < 4; r++) {
                        int row = rowA + r;
                        outb[((size_t)((row >> 11) * 8 + hh) * 2048 + (row & 2047)) * 64 + d] =
                            f2bf(acc[i][j][r] + bv);
                    }
                } else {
                    int c2 = col - 512;
                    int hh = c2 >> 6, d = c2 & 63;
                    u32 plo = (u32)f2bf(acc[i][j][0] + bv) | ((u32)f2bf(acc[i][j][1] + bv) << 16);
                    u32 phi = (u32)f2bf(acc[i][j][2] + bv) | ((u32)f2bf(acc[i][j][3] + bv) << 16);
                    uint2 pk; pk.x = plo; pk.y = phi;
                    *(uint2*)&outb2[((size_t)((rowA >> 11) * 8 + hh) * 64 + d) * 2048 + (rowA & 2047)] = pk;
                }
            } else {
#pragma unroll
                for (int r = 0; r < 4; r++) {
                    int row = rowA + r;
                    float val = acc[i][j][r] + bv;
                    if (MODE == 1) {
                        outb[(size_t)row * N + col] = f2bf(val);
                    } else {
                        size_t idx = (size_t)row * N + col;
                        outf[idx] = val + res[idx];
                    }
                }
            }
        }
    }
}

// ---------------------------------------------------------------------------
// AA[tok] = 0.125 * sum_d q[tok][d]^2, q = qbuf [32*2048][64] bf16
__global__ __launch_bounds__(256) void aa_kernel(const u16* __restrict__ q,
                                                 float* __restrict__ aa) {
    int t = threadIdx.x;
    int tok = blockIdx.x * 32 + (t >> 3);
    int l8 = t & 7;
    const u16* row = q + (size_t)tok * 64 + l8 * 8;
    uint4 u = *(const uint4*)row;
    u32 c[4] = {u.x, u.y, u.z, u.w};
    float s = 0.f;
#pragma unroll
    for (int k = 0; k < 4; k++) {
        float a = bf2f((u16)(c[k] & 0xffff));
        float b = bf2f((u16)(c[k] >> 16));
        s += a * a + b * b;
    }
    s += __shfl_xor(s, 1); s += __shfl_xor(s, 2); s += __shfl_xor(s, 4);
    if (l8 == 0) aa[tok] = s * 0.125f;
}

// ---------------------------------------------------------------------------
// MFMA flash L2-attention, S^T formulation, static max (=0 since K=Q).
// qbuf [bh][2048][64]; vtbuf [bh][64][2048]; aas = 0.125*||q||^2.
// Block (itile of 64 rows, bh) -> grid (32,32); wave w owns i-rows w*16..+15.
// p = exp(0.25*S - aa_j - aa_i); P wave-local (no barrier around PV).
__global__ __launch_bounds__(256) void attn_mfma(const u16* __restrict__ qbuf,
                                                 const u16* __restrict__ vtbuf,
                                                 const float* __restrict__ aas,
                                                 u16* __restrict__ out) {
    __shared__ u16 Qj[64][72];      // j-token rows [j][d]
    __shared__ u16 VT[64][72];      // V^T rows [d][j]
    __shared__ u16 Pl[4][16][72];   // per-wave P [i-local][j]
    int itile = blockIdx.x, bh = blockIdx.y;
    const u16* qb = qbuf + (size_t)bh * 2048 * 64;
    const u16* vtb = vtbuf + (size_t)bh * 64 * 2048;
    const float* aab = aas + (size_t)bh * 2048;
    int t = threadIdx.x;
    int wave = t >> 6, lane = t & 63, quad = lane >> 4, l16 = lane & 15;
    int ibase = itile * 64 + wave * 16;
    // Qi B-fragments in registers: B[n=i][k=d]
    bf16x8 qf0 = *(const bf16x8*)(qb + (size_t)(ibase + l16) * 64 + quad * 8);
    bf16x8 qf1 = *(const bf16x8*)(qb + (size_t)(ibase + l16) * 64 + 32 + quad * 8);
    float ci = aab[ibase + l16];
    f32x4 O[4];
#pragma unroll
    for (int nt = 0; nt < 4; nt++) O[nt] = (f32x4){0.f, 0.f, 0.f, 0.f};
    float lr = 0.f;
    int sr = t >> 2, sc = (t & 3) * 16;

    for (int j0 = 0; j0 < 2048; j0 += 64) {
        __syncthreads();   // previous iteration's Qj/VT reads complete
        {   // stage Qj rows [j][d] and VT rows [d][j] — straight copies
            const u16* srcq = qb + (size_t)(j0 + sr) * 64 + sc;
            uint4 qa = *(const uint4*)srcq;
            uint4 qc = *(const uint4*)(srcq + 8);
            const u16* srcv = vtb + (size_t)sr * 2048 + j0 + sc;
            uint4 va = *(const uint4*)srcv;
            uint4 vc = *(const uint4*)(srcv + 8);
            *(uint4*)&Qj[sr][sc] = qa;
            *(uint4*)&Qj[sr][sc + 8] = qc;
            *(uint4*)&VT[sr][sc] = va;
            *(uint4*)&VT[sr][sc + 8] = vc;
        }
        __syncthreads();
        // ---- S^T = Qj . Qi^T (C[m=j][n=i]); softmax weight; pack P ----
#pragma unroll
        for (int jt = 0; jt < 4; jt++) {
            bf16x8 aj0 = *(const bf16x8*)&Qj[jt * 16 + l16][quad * 8];
            bf16x8 aj1 = *(const bf16x8*)&Qj[jt * 16 + l16][32 + quad * 8];
            f32x4 z = {0.f, 0.f, 0.f, 0.f};
            z = __builtin_amdgcn_mfma_f32_16x16x32_bf16(aj0, qf0, z, 0, 0, 0);
            z = __builtin_amdgcn_mfma_f32_16x16x32_bf16(aj1, qf1, z, 0, 0, 0);
            float4 aav = *(const float4*)(aab + j0 + jt * 16 + quad * 4);
            float p0 = __expf(z[0] * 0.25f - aav.x - ci);
            float p1 = __expf(z[1] * 0.25f - aav.y - ci);
            float p2 = __expf(z[2] * 0.25f - aav.z - ci);
            float p3 = __expf(z[3] * 0.25f - aav.w - ci);
            lr += p0 + p1 + p2 + p3;
            uint2 pk;
            pk.x = (u32)f2bf(p0) | ((u32)f2bf(p1) << 16);
            pk.y = (u32)f2bf(p2) | ((u32)f2bf(p3) << 16);
            *(uint2*)&Pl[wave][l16][jt * 16 + quad * 4] = pk;
        }
        // ---- O += P @ V : A = Pl rows (wave-local), B = VT rows ----
#pragma unroll
        for (int c = 0; c < 2; c++) {
            bf16x8 pa = *(const bf16x8*)&Pl[wave][l16][c * 32 + quad * 8];
#pragma unroll
            for (int nt = 0; nt < 4; nt++) {
                bf16x8 vf = *(const bf16x8*)&VT[nt * 16 + l16][c * 32 + quad * 8];
                O[nt] = __builtin_amdgcn_mfma_f32_16x16x32_bf16(pa, vf, O[nt], 0, 0, 0);
            }
        }
    }
    // epilogue: lr lives per lane for col i=l16; reduce across quads
    lr += __shfl_xor(lr, 16);
    lr += __shfl_xor(lr, 32);
    float inv = 1.f / lr;
    int b = bh >> 3, h = bh & 7;
#pragma unroll
    for (int r = 0; r < 4; r++) {
        float invr = __shfl(inv, quad * 4 + r);   // lane qr holds inv for i=qr
        size_t row = (size_t)(b * 2048 + ibase + quad * 4 + r);
        u16* o = out + row * 512 + h * 64 + l16;
        o[0]  = f2bf(O[0][r] * invr);
        o[16] = f2bf(O[1][r] * invr);
        o[32] = f2bf(O[2][r] * invr);
        o[48] = f2bf(O[3][r] * invr);
    }
}

// ---------------------------------------------------------------------------
// GEGLU: g[m,c] = h[m,c] * gelu(h[m,2048+c]),  h [8192][4096] bf16
__global__ __launch_bounds__(256) void geglu_kernel(const u16* __restrict__ h,
                                                    u16* __restrict__ g) {
    size_t i = ((size_t)blockIdx.x * 256 + threadIdx.x) * 4;
    size_t m = i >> 11;
    int c = (int)(i & 2047);
    const u16* p = h + m * 4096 + c;
    uint2 ua = *(const uint2*)p;
    uint2 ug = *(const uint2*)(p + 2048);
    float a0 = bf2f((u16)(ua.x & 0xffff)), a1 = bf2f((u16)(ua.x >> 16));
    float a2 = bf2f((u16)(ua.y & 0xffff)), a3 = bf2f((u16)(ua.y >> 16));
    float g0 = bf2f((u16)(ug.x & 0xffff)), g1 = bf2f((u16)(ug.x >> 16));
    float g2 = bf2f((u16)(ug.y & 0xffff)), g3 = bf2f((u16)(ug.y >> 16));
    float r0 = a0 * gelu_exact(g0);
    float r1 = a1 * gelu_exact(g1);
    float r2 = a2 * gelu_exact(g2);
    float r3 = a3 * gelu_exact(g3);
    uint2 o;
    o.x = (u32)f2bf(r0) | ((u32)f2bf(r1) << 16);
    o.y = (u32)f2bf(r2) | ((u32)f2bf(r3) << 16);
    *(uint2*)(g + m * 2048 + c) = o;
}

// ---------------------------------------------------------------------------
extern "C" void kernel_launch(void* const* d_in, const int* in_sizes, int n_in,
                              void* d_out, int out_size, void* d_ws, size_t ws_size,
                              hipStream_t stream) {
    const float* x      = (const float*)d_in[0];
    const float* sa_w   = (const float*)d_in[1];
    const float* sa_b   = (const float*)d_in[2];
    const float* ca_w   = (const float*)d_in[3];
    const float* ca_b   = (const float*)d_in[4];
    const float* ffn_w  = (const float*)d_in[5];
    const float* ffn_b  = (const float*)d_in[6];
    const float* a1_wq  = (const float*)d_in[7];
    const float* a1_bq  = (const float*)d_in[8];
    const float* a1_wv  = (const float*)d_in[9];
    const float* a1_bv  = (const float*)d_in[10];
    const float* a1_wo  = (const float*)d_in[11];
    const float* a1_bo  = (const float*)d_in[12];
    const float* a2_wq  = (const float*)d_in[13];
    const float* a2_bq  = (const float*)d_in[14];
    const float* a2_wv  = (const float*)d_in[15];
    const float* a2_bv  = (const float*)d_in[16];
    const float* a2_wo  = (const float*)d_in[17];
    const float* a2_bo  = (const float*)d_in[18];
    const float* ff_w1  = (const float*)d_in[19];
    const float* ff_b1  = (const float*)d_in[20];
    const float* ff_w2  = (const float*)d_in[21];
    const float* ff_b2  = (const float*)d_in[22];

    char* ws = (char*)d_ws;
    const size_t MB = 1ull << 20;
    float* x_res   = (float*)(ws);              // 16 MB fp32 residual stream
    u16* xn        = (u16*)(ws + 16 * MB);      // 8 MB normed activations (bf16)
    u16* wT_a1qv   = (u16*)(ws + 24 * MB);      // 1 MB [1024][512] (wq^T | wv^T)
    u16* wT_a2qv   = (u16*)(ws + 25 * MB);      // 1 MB
    u16* wT_a1o    = (u16*)(ws + 26 * MB);      // 0.5 MB
    u16* wT_a2o    = (u16*)(ws + 26 * MB + 512 * 1024);
    u16* wT_ff1    = (u16*)(ws + 27 * MB);      // 4 MB [4096][512]
    u16* wT_ff2    = (u16*)(ws + 31 * MB);      // 2 MB [512][2048]
    // attn-phase buffers (overlap with ffn-phase hbuf)
    u16* qbuf      = (u16*)(ws + 34 * MB);      // 8 MB [bh][2048][64]
    u16* vtbuf     = (u16*)(ws + 42 * MB);      // 8 MB [bh][64][2048]
    float* aab     = (float*)(ws + 50 * MB);    // 256 KB (0.125*||q||^2)
    u16* attn_o    = (u16*)(ws + 51 * MB);      // 8 MB bf16 [8192][512]
    // ffn-phase buffers
    u16* hbuf      = (u16*)(ws + 34 * MB);      // 64 MB [8192][4096] bf16
    u16* gbuf      = (u16*)(ws + 98 * MB);      // 32 MB [8192][2048] bf16

    (void)in_sizes; (void)n_in; (void)out_size; (void)ws_size;

    // weight transposes (fp32 -> bf16 [N][K]); q|v concatenated
    transpose_f32_bf16<<<dim3(16, 16), 256, 0, stream>>>(a1_wq, wT_a1qv, 512, 512);
    transpose_f32_bf16<<<dim3(16, 16), 256, 0, stream>>>(a1_wv, wT_a1qv + 512 * 512, 512, 512);
    transpose_f32_bf16<<<dim3(16, 16), 256, 0, stream>>>(a2_wq, wT_a2qv, 512, 512);
    transpose_f32_bf16<<<dim3(16, 16), 256, 0, stream>>>(a2_wv, wT_a2qv + 512 * 512, 512, 512);
    transpose_f32_bf16<<<dim3(16, 16), 256, 0, stream>>>(a1_wo, wT_a1o, 512, 512);
    transpose_f32_bf16<<<dim3(16, 16), 256, 0, stream>>>(a2_wo, wT_a2o, 512, 512);
    transpose_f32_bf16<<<dim3(128, 16), 256, 0, stream>>>(ff_w1, wT_ff1, 512, 4096);
    transpose_f32_bf16<<<dim3(16, 64), 256, 0, stream>>>(ff_w2, wT_ff2, 2048, 512);

    // === attention 1 (self) ===
    ln_kernel<<<8192, 256, 0, stream>>>(x, sa_w, sa_b, xn);
    gemm128<4><<<dim3(64, 8), 256, 0, stream>>>(xn, wT_a1qv, a1_bq, a1_bv, nullptr, nullptr, qbuf, vtbuf, 8192, 1024, 512);
    aa_kernel<<<2048, 256, 0, stream>>>(qbuf, aab);
    attn_mfma<<<dim3(32, 32), 256, 0, stream>>>(qbuf, vtbuf, aab, attn_o);
    gemm128<2><<<dim3(64, 4), 256, 0, stream>>>(attn_o, wT_a1o, a1_bo, nullptr, x, x_res, nullptr, nullptr, 8192, 512, 512);

    // === attention 2 ("cross", k=q, v from x) ===
    ln_kernel<<<8192, 256, 0, stream>>>(x_res, ca_w, ca_b, xn);
    gemm128<4><<<dim3(64, 8), 256, 0, stream>>>(xn, wT_a2qv, a2_bq, a2_bv, nullptr, nullptr, qbuf, vtbuf, 8192, 1024, 512);
    aa_kernel<<<2048, 256, 0, stream>>>(qbuf, aab);
    attn_mfma<<<dim3(32, 32), 256, 0, stream>>>(qbuf, vtbuf, aab, attn_o);
    gemm128<2><<<dim3(64, 4), 256, 0, stream>>>(attn_o, wT_a2o, a2_bo, nullptr, x_res, x_res, nullptr, nullptr, 8192, 512, 512);

    // === GEGLU FFN ===
    ln_kernel<<<8192, 256, 0, stream>>>(x_res, ffn_w, ffn_b, xn);
    gemm128<1><<<dim3(64, 32), 256, 0, stream>>>(xn, wT_ff1, ff_b1, nullptr, nullptr, nullptr, hbuf, nullptr, 8192, 4096, 512);
    geglu_kernel<<<16384, 256, 0, stream>>>(hbuf, gbuf);
    gemm128<2><<<dim3(64, 4), 256, 0, stream>>>(gbuf, wT_ff2, ff_b2, nullptr, x_res, (float*)d_out, nullptr, nullptr, 8192, 512, 2048);
}

// Round 8
// 462.133 us; speedup vs baseline: 1.1482x; 1.0550x over previous
//
#include <hip/hip_runtime.h>
#include <hip/hip_bf16.h>

// ---------------------------------------------------------------------------
// BasicTransformerBlock (l2-attention x2 + GEGLU FFN), MI355X gfx950
// Round 8: round-7 structure + CRITICAL FIX: drain vmcnt(0) after each GEMM
// K-loop — the last iteration's dummy global_load_lds prefetch must not be
// in flight at s_endpgm (LDS is deallocated; the DMA lands in the NEXT
// workgroup's LDS -> race seen in round 7's post-timing divergence).
// ---------------------------------------------------------------------------

typedef short bf16x8 __attribute__((ext_vector_type(8)));
typedef float f32x4 __attribute__((ext_vector_type(4)));
typedef unsigned short u16;
typedef unsigned int u32;

__device__ __forceinline__ float bf2f(u16 u) {
    return __uint_as_float(((u32)u) << 16);
}
__device__ __forceinline__ u16 f2bf(float f) {
    u32 u = __float_as_uint(f);
    u32 rb = ((u >> 16) & 1u) + 0x7fffu;   // round-to-nearest-even
    return (u16)((u + rb) >> 16);
}
__device__ __forceinline__ float gelu_exact(float x) {
    return 0.5f * x * (1.f + erff(x * 0.7071067811865475f));
}
__device__ __forceinline__ void gl2lds16(const u16* g, u16* l) {
    __builtin_amdgcn_global_load_lds(
        (const __attribute__((address_space(1))) void*)(unsigned long long)(uintptr_t)g,
        (__attribute__((address_space(3))) void*)(unsigned long long)(uintptr_t)l,
        16, 0, 0);
}

// ---------------------------------------------------------------------------
// fp32 [R][C] -> bf16 [C][R] transpose (weight prep)
__global__ __launch_bounds__(256) void transpose_f32_bf16(const float* __restrict__ in,
                                                          u16* __restrict__ out,
                                                          int R, int C) {
    __shared__ float tile[32][33];
    int bx = blockIdx.x, by = blockIdx.y;
    int t = threadIdx.x;
    int c = t & 31, r0 = (t >> 5) * 4;
#pragma unroll
    for (int i = 0; i < 4; i++)
        tile[r0 + i][c] = in[(size_t)(by * 32 + r0 + i) * C + bx * 32 + c];
    __syncthreads();
#pragma unroll
    for (int i = 0; i < 4; i++)
        out[(size_t)(bx * 32 + r0 + i) * R + by * 32 + c] = f2bf(tile[c][r0 + i]);
}

// ---------------------------------------------------------------------------
// LayerNorm: x fp32 [rows][512] -> out bf16, one block per row
__global__ __launch_bounds__(256) void ln_kernel(const float* __restrict__ x,
                                                 const float* __restrict__ w,
                                                 const float* __restrict__ b,
                                                 u16* __restrict__ out) {
    int row = blockIdx.x, t = threadIdx.x;
    const float* xr = x + (size_t)row * 512;
    float2 v = *(const float2*)(xr + t * 2);
    float s1 = v.x + v.y;
    float s2 = v.x * v.x + v.y * v.y;
#pragma unroll
    for (int m = 1; m < 64; m <<= 1) {
        s1 += __shfl_xor(s1, m);
        s2 += __shfl_xor(s2, m);
    }
    __shared__ float r1[4], r2[4];
    int wave = t >> 6, lane = t & 63;
    if (lane == 0) { r1[wave] = s1; r2[wave] = s2; }
    __syncthreads();
    float tot1 = r1[0] + r1[1] + r1[2] + r1[3];
    float tot2 = r2[0] + r2[1] + r2[2] + r2[3];
    float mu = tot1 * (1.f / 512.f);
    float var = tot2 * (1.f / 512.f) - mu * mu;
    float rs = rsqrtf(var + 1e-5f);
    float2 wv = *(const float2*)(w + t * 2);
    float2 bv = *(const float2*)(b + t * 2);
    float o0 = (v.x - mu) * rs * wv.x + bv.x;
    float o1 = (v.y - mu) * rs * wv.y + bv.y;
    u32 pack = (u32)f2bf(o0) | ((u32)f2bf(o1) << 16);
    *(u32*)(out + (size_t)row * 512 + t * 2) = pack;
}

// ---------------------------------------------------------------------------
// Square 128x128 MFMA GEMM (double-buffered, vmcnt(4) pipelined). MODE 1 only.
template <int MODE>
__global__ __launch_bounds__(256) void gemm128(const u16* __restrict__ A,
                                               const u16* __restrict__ BT,
                                               const float* __restrict__ bias,
                                               u16* __restrict__ outb,
                                               int M, int N, int K) {
    __shared__ u16 As[2][128 * 32];
    __shared__ u16 Bs[2][128 * 32];
    int t = threadIdx.x;
    int wave = t >> 6, lane = t & 63, quad = lane >> 4, l16 = lane & 15;
    int m0 = blockIdx.x * 128, n0 = blockIdx.y * 128;
    int wm = (wave >> 1) * 64, wn = (wave & 1) * 64;
    f32x4 acc[4][4];
#pragma unroll
    for (int i = 0; i < 4; i++)
#pragma unroll
        for (int j = 0; j < 4; j++) acc[i][j] = (f32x4){0.f, 0.f, 0.f, 0.f};
    const u16* Ag = A + (size_t)(m0 + wave * 32 + (lane >> 2)) * K + (lane & 3) * 8;
    const u16* Bg = BT + (size_t)(n0 + wave * 32 + (lane >> 2)) * K + (lane & 3) * 8;
    int lo = wave * 32 * 32;
    const size_t rstep = (size_t)16 * K;
    gl2lds16(Ag, &As[0][lo]);
    gl2lds16(Ag + rstep, &As[0][lo + 16 * 32]);
    gl2lds16(Bg, &Bs[0][lo]);
    gl2lds16(Bg + rstep, &Bs[0][lo + 16 * 32]);
    int buf = 0;
    for (int k0 = 0; k0 < K; k0 += 32, buf ^= 1) {
        int kn = (k0 + 32 < K) ? (k0 + 32) : k0;
        int nb = buf ^ 1;
        asm volatile("s_waitcnt lgkmcnt(0)\n\ts_barrier" ::: "memory");
        gl2lds16(Ag + kn, &As[nb][lo]);
        gl2lds16(Ag + kn + rstep, &As[nb][lo + 16 * 32]);
        gl2lds16(Bg + kn, &Bs[nb][lo]);
        gl2lds16(Bg + kn + rstep, &Bs[nb][lo + 16 * 32]);
        asm volatile("s_waitcnt vmcnt(4)\n\ts_barrier" ::: "memory");
        bf16x8 a[4], b[4];
#pragma unroll
        for (int i = 0; i < 4; i++) {
            a[i] = *(const bf16x8*)&As[buf][(wm + i * 16 + l16) * 32 + quad * 8];
            b[i] = *(const bf16x8*)&Bs[buf][(wn + i * 16 + l16) * 32 + quad * 8];
        }
#pragma unroll
        for (int i = 0; i < 4; i++)
#pragma unroll
            for (int j = 0; j < 4; j++)
                acc[i][j] = __builtin_amdgcn_mfma_f32_16x16x32_bf16(a[i], b[j], acc[i][j], 0, 0, 0);
    }
    // CRITICAL: drain in-flight global_load_lds before s_endpgm (LDS is
    // deallocated at wave end; stale DMA would corrupt the next WG's LDS).
    asm volatile("s_waitcnt vmcnt(0)" ::: "memory");
    int row_base = m0 + wm + quad * 4;
    int col_base = n0 + wn + l16;
#pragma unroll
    for (int j = 0; j < 4; j++) {
        int col = col_base + j * 16;
        float bv = bias[col];
#pragma unroll
        for (int i = 0; i < 4; i++) {
#pragma unroll
            for (int r = 0; r < 4; r++) {
                int row = row_base + i * 16 + r;
                outb[(size_t)row * N + col] = f2bf(acc[i][j][r] + bv);
            }
        }
    }
}

// ---------------------------------------------------------------------------
// Rect 128x64 MFMA GEMM (double-buffered, vmcnt(3)). 4 waves, wave w owns
// rows w*32..+31, all 64 cols. MODE 2: fp32 out = acc+res | 4: qv split:
//   col<512 (q): qbuf [(b*8+h)][n][64]
//   col>=512 (v): vtp [(b*8+h)][64][2048] with j-cols PERMUTED per aligned
//   32-block: a=(n%32)/4 -> slotbase=(a%4)*8+(a/4)*4 (matches attn PV k-order)
template <int MODE>
__global__ __launch_bounds__(256) void gemm_rect(const u16* __restrict__ A,
                                                 const u16* __restrict__ BT,
                                                 const float* __restrict__ bias,
                                                 const float* __restrict__ bias2,
                                                 const float* __restrict__ res,
                                                 float* __restrict__ outf,
                                                 u16* __restrict__ outb,
                                                 u16* __restrict__ outb2,
                                                 int M, int N, int K) {
    __shared__ u16 As[2][128 * 32];
    __shared__ u16 Bs[2][64 * 32];
    int t = threadIdx.x;
    int wave = t >> 6, lane = t & 63, quad = lane >> 4, l16 = lane & 15;
    int m0 = blockIdx.x * 128, n0 = blockIdx.y * 64;
    f32x4 acc[2][4];
#pragma unroll
    for (int i = 0; i < 2; i++)
#pragma unroll
        for (int j = 0; j < 4; j++) acc[i][j] = (f32x4){0.f, 0.f, 0.f, 0.f};
    const u16* Ag = A + (size_t)(m0 + wave * 32 + (lane >> 2)) * K + (lane & 3) * 8;
    const u16* Bg = BT + (size_t)(n0 + wave * 16 + (lane >> 2)) * K + (lane & 3) * 8;
    int loA = wave * 32 * 32;
    int loB = wave * 16 * 32;
    const size_t rstep = (size_t)16 * K;
    gl2lds16(Ag, &As[0][loA]);
    gl2lds16(Ag + rstep, &As[0][loA + 16 * 32]);
    gl2lds16(Bg, &Bs[0][loB]);
    int buf = 0;
    for (int k0 = 0; k0 < K; k0 += 32, buf ^= 1) {
        int kn = (k0 + 32 < K) ? (k0 + 32) : k0;
        int nb = buf ^ 1;
        asm volatile("s_waitcnt lgkmcnt(0)\n\ts_barrier" ::: "memory");
        gl2lds16(Ag + kn, &As[nb][loA]);
        gl2lds16(Ag + kn + rstep, &As[nb][loA + 16 * 32]);
        gl2lds16(Bg + kn, &Bs[nb][loB]);
        asm volatile("s_waitcnt vmcnt(3)\n\ts_barrier" ::: "memory");
        bf16x8 a[2], b[4];
#pragma unroll
        for (int i = 0; i < 2; i++)
            a[i] = *(const bf16x8*)&As[buf][(wave * 32 + i * 16 + l16) * 32 + quad * 8];
#pragma unroll
        for (int j = 0; j < 4; j++)
            b[j] = *(const bf16x8*)&Bs[buf][(j * 16 + l16) * 32 + quad * 8];
#pragma unroll
        for (int i = 0; i < 2; i++)
#pragma unroll
            for (int j = 0; j < 4; j++)
                acc[i][j] = __builtin_amdgcn_mfma_f32_16x16x32_bf16(a[i], b[j], acc[i][j], 0, 0, 0);
    }
    // CRITICAL: drain in-flight global_load_lds before s_endpgm (see gemm128).
    asm volatile("s_waitcnt vmcnt(0)" ::: "memory");
    int row_base = m0 + wave * 32 + quad * 4;
#pragma unroll
    for (int j = 0; j < 4; j++) {
        int col = n0 + j * 16 + l16;
        float bv;
        if (MODE == 4) bv = (col < 512) ? bias[col] : bias2[col - 512];
        else bv = bias[col];
#pragma unroll
        for (int i = 0; i < 2; i++) {
            int rowA = row_base + i * 16;
            if (MODE == 4) {
                if (col < 512) {
                    int hh = col >> 6, d = col & 63;
#pragma unroll
                    for (int r = 0; r < 4; r++) {
                        int row = rowA + r;
                        outb[((size_t)((row >> 11) * 8 + hh) * 2048 + (row & 2047)) * 64 + d] =
                            f2bf(acc[i][j][r] + bv);
                    }
                } else {
                    int c2 = col - 512;
                    int hh = c2 >> 6, d = c2 & 63;
                    int n = rowA & 2047;
                    int a4 = (n >> 2) & 7;
                    int ncol = (n & ~31) + ((a4 & 3) << 3) + ((a4 >> 2) << 2);
                    u32 plo = (u32)f2bf(acc[i][j][0] + bv) | ((u32)f2bf(acc[i][j][1] + bv) << 16);
                    u32 phi = (u32)f2bf(acc[i][j][2] + bv) | ((u32)f2bf(acc[i][j][3] + bv) << 16);
                    uint2 pk; pk.x = plo; pk.y = phi;
                    *(uint2*)&outb2[((size_t)((rowA >> 11) * 8 + hh) * 64 + d) * 2048 + ncol] = pk;
                }
            } else {
#pragma unroll
                for (int r = 0; r < 4; r++) {
                    size_t idx = (size_t)(rowA + r) * N + col;
                    outf[idx] = acc[i][j][r] + bv + res[idx];
                }
            }
        }
    }
}

// ---------------------------------------------------------------------------
// AA[tok] = 0.125 * sum_d q[tok][d]^2, q = qbuf [32*2048][64] bf16
__global__ __launch_bounds__(256) void aa_kernel(const u16* __restrict__ q,
                                                 float* __restrict__ aa) {
    int t = threadIdx.x;
    int tok = blockIdx.x * 32 + (t >> 3);
    int l8 = t & 7;
    const u16* row = q + (size_t)tok * 64 + l8 * 8;
    uint4 u = *(const uint4*)row;
    u32 c[4] = {u.x, u.y, u.z, u.w};
    float s = 0.f;
#pragma unroll
    for (int k = 0; k < 4; k++) {
        float a = bf2f((u16)(c[k] & 0xffff));
        float b = bf2f((u16)(c[k] >> 16));
        s += a * a + b * b;
    }
    s += __shfl_xor(s, 1); s += __shfl_xor(s, 2); s += __shfl_xor(s, 4);
    if (l8 == 0) aa[tok] = s * 0.125f;
}

// ---------------------------------------------------------------------------
// MFMA flash L2-attention, S^T formulation, NO P round-trip.
// qbuf [bh][2048][64]; vtp [bh][64][2048] j-permuted; aas = 0.125*||q||^2.
// S^T C-layout (col=i=l16, rows j=jt*16+quad*4+r) IS the PV A-fragment under
// the k-permutation sigma per 32-j block — vtp columns pre-permuted to match.
__global__ __launch_bounds__(256) void attn_mfma(const u16* __restrict__ qbuf,
                                                 const u16* __restrict__ vtp,
                                                 const float* __restrict__ aas,
                                                 u16* __restrict__ out) {
    __shared__ u16 Qj[64][72];      // j-token rows [j][d] (true j order)
    __shared__ u16 VT[64][72];      // V^T rows [d][j-permuted]
    int itile = blockIdx.x, bh = blockIdx.y;
    const u16* qb = qbuf + (size_t)bh * 2048 * 64;
    const u16* vtb = vtp + (size_t)bh * 64 * 2048;
    const float* aab = aas + (size_t)bh * 2048;
    int t = threadIdx.x;
    int wave = t >> 6, lane = t & 63, quad = lane >> 4, l16 = lane & 15;
    int ibase = itile * 64 + wave * 16;
    // Qi B-fragments in registers: B[n=i][k=d]
    bf16x8 qf0 = *(const bf16x8*)(qb + (size_t)(ibase + l16) * 64 + quad * 8);
    bf16x8 qf1 = *(const bf16x8*)(qb + (size_t)(ibase + l16) * 64 + 32 + quad * 8);
    float ci = aab[ibase + l16];
    f32x4 O[4];
#pragma unroll
    for (int nt = 0; nt < 4; nt++) O[nt] = (f32x4){0.f, 0.f, 0.f, 0.f};
    float lr = 0.f;
    int sr = t >> 2, sc = (t & 3) * 16;
    // register prefetch of tile j0=0
    uint4 nq0, nq1, nv0, nv1;
    {
        const u16* srcq = qb + (size_t)sr * 64 + sc;
        nq0 = *(const uint4*)srcq;
        nq1 = *(const uint4*)(srcq + 8);
        const u16* srcv = vtb + (size_t)sr * 2048 + sc;
        nv0 = *(const uint4*)srcv;
        nv1 = *(const uint4*)(srcv + 8);
    }
    for (int j0 = 0; j0 < 2048; j0 += 64) {
        __syncthreads();   // previous iteration's LDS reads complete
        *(uint4*)&Qj[sr][sc] = nq0;
        *(uint4*)&Qj[sr][sc + 8] = nq1;
        *(uint4*)&VT[sr][sc] = nv0;
        *(uint4*)&VT[sr][sc + 8] = nv1;
        if (j0 + 64 < 2048) {   // prefetch next tile into regs (covered by compute)
            const u16* srcq = qb + (size_t)(j0 + 64 + sr) * 64 + sc;
            nq0 = *(const uint4*)srcq;
            nq1 = *(const uint4*)(srcq + 8);
            const u16* srcv = vtb + (size_t)sr * 2048 + (j0 + 64) + sc;
            nv0 = *(const uint4*)srcv;
            nv1 = *(const uint4*)(srcv + 8);
        }
        __syncthreads();
#pragma unroll
        for (int c = 0; c < 2; c++) {
            int j1 = c * 32, j2 = c * 32 + 16;
            bf16x8 a10 = *(const bf16x8*)&Qj[j1 + l16][quad * 8];
            bf16x8 a11 = *(const bf16x8*)&Qj[j1 + l16][32 + quad * 8];
            f32x4 s0 = {0.f, 0.f, 0.f, 0.f};
            s0 = __builtin_amdgcn_mfma_f32_16x16x32_bf16(a10, qf0, s0, 0, 0, 0);
            s0 = __builtin_amdgcn_mfma_f32_16x16x32_bf16(a11, qf1, s0, 0, 0, 0);
            bf16x8 a20 = *(const bf16x8*)&Qj[j2 + l16][quad * 8];
            bf16x8 a21 = *(const bf16x8*)&Qj[j2 + l16][32 + quad * 8];
            f32x4 s1 = {0.f, 0.f, 0.f, 0.f};
            s1 = __builtin_amdgcn_mfma_f32_16x16x32_bf16(a20, qf0, s1, 0, 0, 0);
            s1 = __builtin_amdgcn_mfma_f32_16x16x32_bf16(a21, qf1, s1, 0, 0, 0);
            float4 aav0 = *(const float4*)(aab + j0 + j1 + quad * 4);
            float4 aav1 = *(const float4*)(aab + j0 + j2 + quad * 4);
            float p0 = __expf(s0[0] * 0.25f - aav0.x - ci);
            float p1 = __expf(s0[1] * 0.25f - aav0.y - ci);
            float p2 = __expf(s0[2] * 0.25f - aav0.z - ci);
            float p3 = __expf(s0[3] * 0.25f - aav0.w - ci);
            float p4 = __expf(s1[0] * 0.25f - aav1.x - ci);
            float p5 = __expf(s1[1] * 0.25f - aav1.y - ci);
            float p6 = __expf(s1[2] * 0.25f - aav1.z - ci);
            float p7 = __expf(s1[3] * 0.25f - aav1.w - ci);
            lr += (p0 + p1 + p2 + p3) + (p4 + p5 + p6 + p7);
            bf16x8 pa;
            pa[0] = (short)f2bf(p0); pa[1] = (short)f2bf(p1);
            pa[2] = (short)f2bf(p2); pa[3] = (short)f2bf(p3);
            pa[4] = (short)f2bf(p4); pa[5] = (short)f2bf(p5);
            pa[6] = (short)f2bf(p6); pa[7] = (short)f2bf(p7);
#pragma unroll
            for (int nt = 0; nt < 4; nt++) {
                bf16x8 vf = *(const bf16x8*)&VT[nt * 16 + l16][c * 32 + quad * 8];
                O[nt] = __builtin_amdgcn_mfma_f32_16x16x32_bf16(pa, vf, O[nt], 0, 0, 0);
            }
        }
    }
    // epilogue
    lr += __shfl_xor(lr, 16);
    lr += __shfl_xor(lr, 32);
    float inv = 1.f / lr;
    int b = bh >> 3, h = bh & 7;
#pragma unroll
    for (int r = 0; r < 4; r++) {
        float invr = __shfl(inv, quad * 4 + r);
        size_t row = (size_t)(b * 2048 + ibase + quad * 4 + r);
        u16* o = out + row * 512 + h * 64 + l16;
        o[0]  = f2bf(O[0][r] * invr);
        o[16] = f2bf(O[1][r] * invr);
        o[32] = f2bf(O[2][r] * invr);
        o[48] = f2bf(O[3][r] * invr);
    }
}

// ---------------------------------------------------------------------------
// GEGLU: g[m,c] = h[m,c] * gelu(h[m,2048+c]),  h [8192][4096] bf16
__global__ __launch_bounds__(256) void geglu_kernel(const u16* __restrict__ h,
                                                    u16* __restrict__ g) {
    size_t i = ((size_t)blockIdx.x * 256 + threadIdx.x) * 4;
    size_t m = i >> 11;
    int c = (int)(i & 2047);
    const u16* p = h + m * 4096 + c;
    uint2 ua = *(const uint2*)p;
    uint2 ug = *(const uint2*)(p + 2048);
    float a0 = bf2f((u16)(ua.x & 0xffff)), a1 = bf2f((u16)(ua.x >> 16));
    float a2 = bf2f((u16)(ua.y & 0xffff)), a3 = bf2f((u16)(ua.y >> 16));
    float g0 = bf2f((u16)(ug.x & 0xffff)), g1 = bf2f((u16)(ug.x >> 16));
    float g2 = bf2f((u16)(ug.y & 0xffff)), g3 = bf2f((u16)(ug.y >> 16));
    float r0 = a0 * gelu_exact(g0);
    float r1 = a1 * gelu_exact(g1);
    float r2 = a2 * gelu_exact(g2);
    float r3 = a3 * gelu_exact(g3);
    uint2 o;
    o.x = (u32)f2bf(r0) | ((u32)f2bf(r1) << 16);
    o.y = (u32)f2bf(r2) | ((u32)f2bf(r3) << 16);
    *(uint2*)(g + m * 2048 + c) = o;
}

// ---------------------------------------------------------------------------
extern "C" void kernel_launch(void* const* d_in, const int* in_sizes, int n_in,
                              void* d_out, int out_size, void* d_ws, size_t ws_size,
                              hipStream_t stream) {
    const float* x      = (const float*)d_in[0];
    const float* sa_w   = (const float*)d_in[1];
    const float* sa_b   = (const float*)d_in[2];
    const float* ca_w   = (const float*)d_in[3];
    const float* ca_b   = (const float*)d_in[4];
    const float* ffn_w  = (const float*)d_in[5];
    const float* ffn_b  = (const float*)d_in[6];
    const float* a1_wq  = (const float*)d_in[7];
    const float* a1_bq  = (const float*)d_in[8];
    const float* a1_wv  = (const float*)d_in[9];
    const float* a1_bv  = (const float*)d_in[10];
    const float* a1_wo  = (const float*)d_in[11];
    const float* a1_bo  = (const float*)d_in[12];
    const float* a2_wq  = (const float*)d_in[13];
    const float* a2_bq  = (const float*)d_in[14];
    const float* a2_wv  = (const float*)d_in[15];
    const float* a2_bv  = (const float*)d_in[16];
    const float* a2_wo  = (const float*)d_in[17];
    const float* a2_bo  = (const float*)d_in[18];
    const float* ff_w1  = (const float*)d_in[19];
    const float* ff_b1  = (const float*)d_in[20];
    const float* ff_w2  = (const float*)d_in[21];
    const float* ff_b2  = (const float*)d_in[22];

    char* ws = (char*)d_ws;
    const size_t MB = 1ull << 20;
    float* x_res   = (float*)(ws);              // 16 MB fp32 residual stream
    u16* xn        = (u16*)(ws + 16 * MB);      // 8 MB normed activations (bf16)
    u16* wT_a1qv   = (u16*)(ws + 24 * MB);      // 1 MB [1024][512] (wq^T | wv^T)
    u16* wT_a2qv   = (u16*)(ws + 25 * MB);      // 1 MB
    u16* wT_a1o    = (u16*)(ws + 26 * MB);      // 0.5 MB
    u16* wT_a2o    = (u16*)(ws + 26 * MB + 512 * 1024);
    u16* wT_ff1    = (u16*)(ws + 27 * MB);      // 4 MB [4096][512]
    u16* wT_ff2    = (u16*)(ws + 31 * MB);      // 2 MB [512][2048]
    // attn-phase buffers (overlap with ffn-phase hbuf)
    u16* qbuf      = (u16*)(ws + 34 * MB);      // 8 MB [bh][2048][64]
    u16* vtp       = (u16*)(ws + 42 * MB);      // 8 MB [bh][64][2048] (j-permuted)
    float* aab     = (float*)(ws + 50 * MB);    // 256 KB (0.125*||q||^2)
    u16* attn_o    = (u16*)(ws + 51 * MB);      // 8 MB bf16 [8192][512]
    // ffn-phase buffers
    u16* hbuf      = (u16*)(ws + 34 * MB);      // 64 MB [8192][4096] bf16
    u16* gbuf      = (u16*)(ws + 98 * MB);      // 32 MB [8192][2048] bf16

    (void)in_sizes; (void)n_in; (void)out_size; (void)ws_size;

    // weight transposes (fp32 -> bf16 [N][K]); q|v concatenated
    transpose_f32_bf16<<<dim3(16, 16), 256, 0, stream>>>(a1_wq, wT_a1qv, 512, 512);
    transpose_f32_bf16<<<dim3(16, 16), 256, 0, stream>>>(a1_wv, wT_a1qv + 512 * 512, 512, 512);
    transpose_f32_bf16<<<dim3(16, 16), 256, 0, stream>>>(a2_wq, wT_a2qv, 512, 512);
    transpose_f32_bf16<<<dim3(16, 16), 256, 0, stream>>>(a2_wv, wT_a2qv + 512 * 512, 512, 512);
    transpose_f32_bf16<<<dim3(16, 16), 256, 0, stream>>>(a1_wo, wT_a1o, 512, 512);
    transpose_f32_bf16<<<dim3(16, 16), 256, 0, stream>>>(a2_wo, wT_a2o, 512, 512);
    transpose_f32_bf16<<<dim3(128, 16), 256, 0, stream>>>(ff_w1, wT_ff1, 512, 4096);
    transpose_f32_bf16<<<dim3(16, 64), 256, 0, stream>>>(ff_w2, wT_ff2, 2048, 512);

    // === attention 1 (self) ===
    ln_kernel<<<8192, 256, 0, stream>>>(x, sa_w, sa_b, xn);
    gemm_rect<4><<<dim3(64, 16), 256, 0, stream>>>(xn, wT_a1qv, a1_bq, a1_bv, nullptr, nullptr, qbuf, vtp, 8192, 1024, 512);
    aa_kernel<<<2048, 256, 0, stream>>>(qbuf, aab);
    attn_mfma<<<dim3(32, 32), 256, 0, stream>>>(qbuf, vtp, aab, attn_o);
    gemm_rect<2><<<dim3(64, 8), 256, 0, stream>>>(attn_o, wT_a1o, a1_bo, nullptr, x, x_res, nullptr, nullptr, 8192, 512, 512);

    // === attention 2 ("cross", k=q, v from x) ===
    ln_kernel<<<8192, 256, 0, stream>>>(x_res, ca_w, ca_b, xn);
    gemm_rect<4><<<dim3(64, 16), 256, 0, stream>>>(xn, wT_a2qv, a2_bq, a2_bv, nullptr, nullptr, qbuf, vtp, 8192, 1024, 512);
    aa_kernel<<<2048, 256, 0, stream>>>(qbuf, aab);
    attn_mfma<<<dim3(32, 32), 256, 0, stream>>>(qbuf, vtp, aab, attn_o);
    gemm_rect<2><<<dim3(64, 8), 256, 0, stream>>>(attn_o, wT_a2o, a2_bo, nullptr, x_res, x_res, nullptr, nullptr, 8192, 512, 512);

    // === GEGLU FFN ===
    ln_kernel<<<8192, 256, 0, stream>>>(x_res, ffn_w, ffn_b, xn);
    gemm128<1><<<dim3(64, 32), 256, 0, stream>>>(xn, wT_ff1, ff_b1, hbuf, 8192, 4096, 512);
    geglu_kernel<<<16384, 256, 0, stream>>>(hbuf, gbuf);
    gemm_rect<2><<<dim3(64, 8), 256, 0, stream>>>(gbuf, wT_ff2, ff_b2, nullptr, x_res, (float*)d_out, nullptr, nullptr, 8192, 512, 2048);
}

// Round 9
// 428.762 us; speedup vs baseline: 1.2375x; 1.0778x over previous
//
#include <hip/hip_runtime.h>
#include <hip/hip_bf16.h>

// ---------------------------------------------------------------------------
// BasicTransformerBlock (l2-attention x2 + GEGLU FFN), MI355X gfx950
// Round 9: round-8 + (1) GEGLU fused into ff1 (dual-B rect GEMM, no hbuf),
// (2) AA fused into qv projection epilogue (no aa_kernel), (3) attention
// P-pack via v_perm truncation (VALU cut). GEMM pipeline/drain unchanged.
// ---------------------------------------------------------------------------

typedef short bf16x8 __attribute__((ext_vector_type(8)));
typedef float f32x4 __attribute__((ext_vector_type(4)));
typedef unsigned short u16;
typedef unsigned int u32;

__device__ __forceinline__ float bf2f(u16 u) {
    return __uint_as_float(((u32)u) << 16);
}
__device__ __forceinline__ u16 f2bf(float f) {
    u32 u = __float_as_uint(f);
    u32 rb = ((u >> 16) & 1u) + 0x7fffu;   // round-to-nearest-even
    return (u16)((u + rb) >> 16);
}
__device__ __forceinline__ float gelu_exact(float x) {
    return 0.5f * x * (1.f + erff(x * 0.7071067811865475f));
}
__device__ __forceinline__ void gl2lds16(const u16* g, u16* l) {
    __builtin_amdgcn_global_load_lds(
        (const __attribute__((address_space(1))) void*)(unsigned long long)(uintptr_t)g,
        (__attribute__((address_space(3))) void*)(unsigned long long)(uintptr_t)l,
        16, 0, 0);
}

// ---------------------------------------------------------------------------
// fp32 [R][C] -> bf16 [C][R] transpose (weight prep)
__global__ __launch_bounds__(256) void transpose_f32_bf16(const float* __restrict__ in,
                                                          u16* __restrict__ out,
                                                          int R, int C) {
    __shared__ float tile[32][33];
    int bx = blockIdx.x, by = blockIdx.y;
    int t = threadIdx.x;
    int c = t & 31, r0 = (t >> 5) * 4;
#pragma unroll
    for (int i = 0; i < 4; i++)
        tile[r0 + i][c] = in[(size_t)(by * 32 + r0 + i) * C + bx * 32 + c];
    __syncthreads();
#pragma unroll
    for (int i = 0; i < 4; i++)
        out[(size_t)(bx * 32 + r0 + i) * R + by * 32 + c] = f2bf(tile[c][r0 + i]);
}

// ---------------------------------------------------------------------------
// LayerNorm: x fp32 [rows][512] -> out bf16, one block per row
__global__ __launch_bounds__(256) void ln_kernel(const float* __restrict__ x,
                                                 const float* __restrict__ w,
                                                 const float* __restrict__ b,
                                                 u16* __restrict__ out) {
    int row = blockIdx.x, t = threadIdx.x;
    const float* xr = x + (size_t)row * 512;
    float2 v = *(const float2*)(xr + t * 2);
    float s1 = v.x + v.y;
    float s2 = v.x * v.x + v.y * v.y;
#pragma unroll
    for (int m = 1; m < 64; m <<= 1) {
        s1 += __shfl_xor(s1, m);
        s2 += __shfl_xor(s2, m);
    }
    __shared__ float r1[4], r2[4];
    int wave = t >> 6, lane = t & 63;
    if (lane == 0) { r1[wave] = s1; r2[wave] = s2; }
    __syncthreads();
    float tot1 = r1[0] + r1[1] + r1[2] + r1[3];
    float tot2 = r2[0] + r2[1] + r2[2] + r2[3];
    float mu = tot1 * (1.f / 512.f);
    float var = tot2 * (1.f / 512.f) - mu * mu;
    float rs = rsqrtf(var + 1e-5f);
    float2 wv = *(const float2*)(w + t * 2);
    float2 bv = *(const float2*)(b + t * 2);
    float o0 = (v.x - mu) * rs * wv.x + bv.x;
    float o1 = (v.y - mu) * rs * wv.y + bv.y;
    u32 pack = (u32)f2bf(o0) | ((u32)f2bf(o1) << 16);
    *(u32*)(out + (size_t)row * 512 + t * 2) = pack;
}

// ---------------------------------------------------------------------------
// ff1+GEGLU fused rect GEMM: A [8192][512] bf16, BT = ff1^T [4096][512].
// Block (bx, by): rows m0=bx*128, cols n0=by*64 of the 2048-wide GEGLU output.
// Stages BOTH B tiles (a-half rows n0.., gate-half rows 2048+n0..).
// Epilogue: g = a * gelu(gate) -> gbuf [8192][2048] bf16.
__global__ __launch_bounds__(256) void gemm_ff1(const u16* __restrict__ A,
                                                const u16* __restrict__ BT,
                                                const float* __restrict__ bias,
                                                u16* __restrict__ gout,
                                                int K) {
    __shared__ u16 As[2][128 * 32];
    __shared__ u16 Bs[2][128 * 32];   // rows 0-63 = a-half, 64-127 = gate-half
    int t = threadIdx.x;
    int wave = t >> 6, lane = t & 63, quad = lane >> 4, l16 = lane & 15;
    int m0 = blockIdx.x * 128, n0 = blockIdx.y * 64;
    f32x4 aacc[2][4], gacc[2][4];
#pragma unroll
    for (int i = 0; i < 2; i++)
#pragma unroll
        for (int j = 0; j < 4; j++) {
            aacc[i][j] = (f32x4){0.f, 0.f, 0.f, 0.f};
            gacc[i][j] = (f32x4){0.f, 0.f, 0.f, 0.f};
        }
    const u16* Ag = A + (size_t)(m0 + wave * 32 + (lane >> 2)) * K + (lane & 3) * 8;
    int brow = (wave < 2) ? (n0 + wave * 32) : (2048 + n0 + (wave - 2) * 32);
    const u16* Bg = BT + (size_t)(brow + (lane >> 2)) * K + (lane & 3) * 8;
    int lo = wave * 32 * 32;
    const size_t rstep = (size_t)16 * K;
    gl2lds16(Ag, &As[0][lo]);
    gl2lds16(Ag + rstep, &As[0][lo + 16 * 32]);
    gl2lds16(Bg, &Bs[0][lo]);
    gl2lds16(Bg + rstep, &Bs[0][lo + 16 * 32]);
    int buf = 0;
    for (int k0 = 0; k0 < K; k0 += 32, buf ^= 1) {
        int kn = (k0 + 32 < K) ? (k0 + 32) : k0;
        int nb = buf ^ 1;
        asm volatile("s_waitcnt lgkmcnt(0)\n\ts_barrier" ::: "memory");
        gl2lds16(Ag + kn, &As[nb][lo]);
        gl2lds16(Ag + kn + rstep, &As[nb][lo + 16 * 32]);
        gl2lds16(Bg + kn, &Bs[nb][lo]);
        gl2lds16(Bg + kn + rstep, &Bs[nb][lo + 16 * 32]);
        asm volatile("s_waitcnt vmcnt(4)\n\ts_barrier" ::: "memory");
        bf16x8 a[2];
#pragma unroll
        for (int i = 0; i < 2; i++)
            a[i] = *(const bf16x8*)&As[buf][(wave * 32 + i * 16 + l16) * 32 + quad * 8];
#pragma unroll
        for (int j = 0; j < 4; j++) {
            bf16x8 ba = *(const bf16x8*)&Bs[buf][(j * 16 + l16) * 32 + quad * 8];
            bf16x8 bg = *(const bf16x8*)&Bs[buf][(64 + j * 16 + l16) * 32 + quad * 8];
#pragma unroll
            for (int i = 0; i < 2; i++) {
                aacc[i][j] = __builtin_amdgcn_mfma_f32_16x16x32_bf16(a[i], ba, aacc[i][j], 0, 0, 0);
                gacc[i][j] = __builtin_amdgcn_mfma_f32_16x16x32_bf16(a[i], bg, gacc[i][j], 0, 0, 0);
            }
        }
    }
    asm volatile("s_waitcnt vmcnt(0)" ::: "memory");   // drain DMA before endpgm
    int row_base = m0 + wave * 32 + quad * 4;
#pragma unroll
    for (int j = 0; j < 4; j++) {
        int col = n0 + j * 16 + l16;
        float ba = bias[col];
        float bg = bias[2048 + col];
#pragma unroll
        for (int i = 0; i < 2; i++) {
#pragma unroll
            for (int r = 0; r < 4; r++) {
                int row = row_base + i * 16 + r;
                float av = aacc[i][j][r] + ba;
                float gv = gacc[i][j][r] + bg;
                gout[(size_t)row * 2048 + col] = f2bf(av * gelu_exact(gv));
            }
        }
    }
}

// ---------------------------------------------------------------------------
// Rect 128x64 MFMA GEMM (double-buffered, vmcnt(3)).
// MODE 2: fp32 out = acc + res | 4: qv split:
//   col<512 (q): qbuf [(b*8+h)][n][64] + fused AA write (aa = 0.125*sum q^2)
//   col>=512 (v): vtp [(b*8+h)][64][2048] j-cols PERMUTED per aligned 32-block
template <int MODE>
__global__ __launch_bounds__(256) void gemm_rect(const u16* __restrict__ A,
                                                 const u16* __restrict__ BT,
                                                 const float* __restrict__ bias,
                                                 const float* __restrict__ bias2,
                                                 const float* __restrict__ res,
                                                 float* __restrict__ outf,
                                                 u16* __restrict__ outb,
                                                 u16* __restrict__ outb2,
                                                 float* __restrict__ aa,
                                                 int M, int N, int K) {
    __shared__ u16 As[2][128 * 32];
    __shared__ u16 Bs[2][64 * 32];
    int t = threadIdx.x;
    int wave = t >> 6, lane = t & 63, quad = lane >> 4, l16 = lane & 15;
    int m0 = blockIdx.x * 128, n0 = blockIdx.y * 64;
    f32x4 acc[2][4];
#pragma unroll
    for (int i = 0; i < 2; i++)
#pragma unroll
        for (int j = 0; j < 4; j++) acc[i][j] = (f32x4){0.f, 0.f, 0.f, 0.f};
    const u16* Ag = A + (size_t)(m0 + wave * 32 + (lane >> 2)) * K + (lane & 3) * 8;
    const u16* Bg = BT + (size_t)(n0 + wave * 16 + (lane >> 2)) * K + (lane & 3) * 8;
    int loA = wave * 32 * 32;
    int loB = wave * 16 * 32;
    const size_t rstep = (size_t)16 * K;
    gl2lds16(Ag, &As[0][loA]);
    gl2lds16(Ag + rstep, &As[0][loA + 16 * 32]);
    gl2lds16(Bg, &Bs[0][loB]);
    int buf = 0;
    for (int k0 = 0; k0 < K; k0 += 32, buf ^= 1) {
        int kn = (k0 + 32 < K) ? (k0 + 32) : k0;
        int nb = buf ^ 1;
        asm volatile("s_waitcnt lgkmcnt(0)\n\ts_barrier" ::: "memory");
        gl2lds16(Ag + kn, &As[nb][loA]);
        gl2lds16(Ag + kn + rstep, &As[nb][loA + 16 * 32]);
        gl2lds16(Bg + kn, &Bs[nb][loB]);
        asm volatile("s_waitcnt vmcnt(3)\n\ts_barrier" ::: "memory");
        bf16x8 a[2], b[4];
#pragma unroll
        for (int i = 0; i < 2; i++)
            a[i] = *(const bf16x8*)&As[buf][(wave * 32 + i * 16 + l16) * 32 + quad * 8];
#pragma unroll
        for (int j = 0; j < 4; j++)
            b[j] = *(const bf16x8*)&Bs[buf][(j * 16 + l16) * 32 + quad * 8];
#pragma unroll
        for (int i = 0; i < 2; i++)
#pragma unroll
            for (int j = 0; j < 4; j++)
                acc[i][j] = __builtin_amdgcn_mfma_f32_16x16x32_bf16(a[i], b[j], acc[i][j], 0, 0, 0);
    }
    asm volatile("s_waitcnt vmcnt(0)" ::: "memory");   // drain DMA before endpgm
    int row_base = m0 + wave * 32 + quad * 4;
    float ssq[2][4];
#pragma unroll
    for (int i = 0; i < 2; i++)
#pragma unroll
        for (int r = 0; r < 4; r++) ssq[i][r] = 0.f;
#pragma unroll
    for (int j = 0; j < 4; j++) {
        int col = n0 + j * 16 + l16;
        float bv;
        if (MODE == 4) bv = (col < 512) ? bias[col] : bias2[col - 512];
        else bv = bias[col];
#pragma unroll
        for (int i = 0; i < 2; i++) {
            int rowA = row_base + i * 16;
            if (MODE == 4) {
                if (col < 512) {
                    int hh = col >> 6, d = col & 63;
#pragma unroll
                    for (int r = 0; r < 4; r++) {
                        int row = rowA + r;
                        float v = acc[i][j][r] + bv;
                        ssq[i][r] += v * v;
                        outb[((size_t)((row >> 11) * 8 + hh) * 2048 + (row & 2047)) * 64 + d] = f2bf(v);
                    }
                } else {
                    int c2 = col - 512;
                    int hh = c2 >> 6, d = c2 & 63;
                    int n = rowA & 2047;
                    int a4 = (n >> 2) & 7;
                    int ncol = (n & ~31) + ((a4 & 3) << 3) + ((a4 >> 2) << 2);
                    u32 plo = (u32)f2bf(acc[i][j][0] + bv) | ((u32)f2bf(acc[i][j][1] + bv) << 16);
                    u32 phi = (u32)f2bf(acc[i][j][2] + bv) | ((u32)f2bf(acc[i][j][3] + bv) << 16);
                    uint2 pk; pk.x = plo; pk.y = phi;
                    *(uint2*)&outb2[((size_t)((rowA >> 11) * 8 + hh) * 64 + d) * 2048 + ncol] = pk;
                }
            } else {
#pragma unroll
                for (int r = 0; r < 4; r++) {
                    size_t idx = (size_t)(rowA + r) * N + col;
                    outf[idx] = acc[i][j][r] + bv + res[idx];
                }
            }
        }
    }
    // fused AA for the q-half (block covers exactly one head's 64 d-cols)
    if (MODE == 4 && n0 < 512) {
        int hh = n0 >> 6;
#pragma unroll
        for (int i = 0; i < 2; i++) {
#pragma unroll
            for (int r = 0; r < 4; r++) {
                float s = ssq[i][r];
                s += __shfl_xor(s, 1); s += __shfl_xor(s, 2);
                s += __shfl_xor(s, 4); s += __shfl_xor(s, 8);
                if (l16 == 0) {
                    int row = row_base + i * 16 + r;
                    aa[(size_t)((row >> 11) * 8 + hh) * 2048 + (row & 2047)] = s * 0.125f;
                }
            }
        }
    }
}

// ---------------------------------------------------------------------------
// MFMA flash L2-attention, S^T formulation, NO P round-trip.
// qbuf [bh][2048][64]; vtp [bh][64][2048] j-permuted; aas = 0.125*||q||^2.
// S^T C-layout (col=i=l16, rows j) IS the PV A-fragment under the baked-in
// k-permutation. P packed via v_perm truncation (positive values).
__global__ __launch_bounds__(256) void attn_mfma(const u16* __restrict__ qbuf,
                                                 const u16* __restrict__ vtp,
                                                 const float* __restrict__ aas,
                                                 u16* __restrict__ out) {
    __shared__ u16 Qj[64][72];
    __shared__ u16 VT[64][72];
    int itile = blockIdx.x, bh = blockIdx.y;
    const u16* qb = qbuf + (size_t)bh * 2048 * 64;
    const u16* vtb = vtp + (size_t)bh * 64 * 2048;
    const float* aab = aas + (size_t)bh * 2048;
    int t = threadIdx.x;
    int wave = t >> 6, lane = t & 63, quad = lane >> 4, l16 = lane & 15;
    int ibase = itile * 64 + wave * 16;
    bf16x8 qf0 = *(const bf16x8*)(qb + (size_t)(ibase + l16) * 64 + quad * 8);
    bf16x8 qf1 = *(const bf16x8*)(qb + (size_t)(ibase + l16) * 64 + 32 + quad * 8);
    float ci = aab[ibase + l16];
    f32x4 O[4];
#pragma unroll
    for (int nt = 0; nt < 4; nt++) O[nt] = (f32x4){0.f, 0.f, 0.f, 0.f};
    float lr = 0.f;
    int sr = t >> 2, sc = (t & 3) * 16;
    uint4 nq0, nq1, nv0, nv1;
    {
        const u16* srcq = qb + (size_t)sr * 64 + sc;
        nq0 = *(const uint4*)srcq;
        nq1 = *(const uint4*)(srcq + 8);
        const u16* srcv = vtb + (size_t)sr * 2048 + sc;
        nv0 = *(const uint4*)srcv;
        nv1 = *(const uint4*)(srcv + 8);
    }
    for (int j0 = 0; j0 < 2048; j0 += 64) {
        __syncthreads();
        *(uint4*)&Qj[sr][sc] = nq0;
        *(uint4*)&Qj[sr][sc + 8] = nq1;
        *(uint4*)&VT[sr][sc] = nv0;
        *(uint4*)&VT[sr][sc + 8] = nv1;
        if (j0 + 64 < 2048) {
            const u16* srcq = qb + (size_t)(j0 + 64 + sr) * 64 + sc;
            nq0 = *(const uint4*)srcq;
            nq1 = *(const uint4*)(srcq + 8);
            const u16* srcv = vtb + (size_t)sr * 2048 + (j0 + 64) + sc;
            nv0 = *(const uint4*)srcv;
            nv1 = *(const uint4*)(srcv + 8);
        }
        __syncthreads();
#pragma unroll
        for (int c = 0; c < 2; c++) {
            int j1 = c * 32, j2 = c * 32 + 16;
            bf16x8 a10 = *(const bf16x8*)&Qj[j1 + l16][quad * 8];
            bf16x8 a11 = *(const bf16x8*)&Qj[j1 + l16][32 + quad * 8];
            f32x4 s0 = {0.f, 0.f, 0.f, 0.f};
            s0 = __builtin_amdgcn_mfma_f32_16x16x32_bf16(a10, qf0, s0, 0, 0, 0);
            s0 = __builtin_amdgcn_mfma_f32_16x16x32_bf16(a11, qf1, s0, 0, 0, 0);
            bf16x8 a20 = *(const bf16x8*)&Qj[j2 + l16][quad * 8];
            bf16x8 a21 = *(const bf16x8*)&Qj[j2 + l16][32 + quad * 8];
            f32x4 s1 = {0.f, 0.f, 0.f, 0.f};
            s1 = __builtin_amdgcn_mfma_f32_16x16x32_bf16(a20, qf0, s1, 0, 0, 0);
            s1 = __builtin_amdgcn_mfma_f32_16x16x32_bf16(a21, qf1, s1, 0, 0, 0);
            float4 aav0 = *(const float4*)(aab + j0 + j1 + quad * 4);
            float4 aav1 = *(const float4*)(aab + j0 + j2 + quad * 4);
            float p0 = __expf(s0[0] * 0.25f - aav0.x - ci);
            float p1 = __expf(s0[1] * 0.25f - aav0.y - ci);
            float p2 = __expf(s0[2] * 0.25f - aav0.z - ci);
            float p3 = __expf(s0[3] * 0.25f - aav0.w - ci);
            float p4 = __expf(s1[0] * 0.25f - aav1.x - ci);
            float p5 = __expf(s1[1] * 0.25f - aav1.y - ci);
            float p6 = __expf(s1[2] * 0.25f - aav1.z - ci);
            float p7 = __expf(s1[3] * 0.25f - aav1.w - ci);
            lr += (p0 + p1 + p2 + p3) + (p4 + p5 + p6 + p7);
            // pack P via byte-perm truncation (positive -> floor, <=0.4% rel)
            bf16x8 pa;
            u32* pu = (u32*)&pa;
            pu[0] = __builtin_amdgcn_perm(__float_as_uint(p1), __float_as_uint(p0), 0x07060302u);
            pu[1] = __builtin_amdgcn_perm(__float_as_uint(p3), __float_as_uint(p2), 0x07060302u);
            pu[2] = __builtin_amdgcn_perm(__float_as_uint(p5), __float_as_uint(p4), 0x07060302u);
            pu[3] = __builtin_amdgcn_perm(__float_as_uint(p7), __float_as_uint(p6), 0x07060302u);
#pragma unroll
            for (int nt = 0; nt < 4; nt++) {
                bf16x8 vf = *(const bf16x8*)&VT[nt * 16 + l16][c * 32 + quad * 8];
                O[nt] = __builtin_amdgcn_mfma_f32_16x16x32_bf16(pa, vf, O[nt], 0, 0, 0);
            }
        }
    }
    lr += __shfl_xor(lr, 16);
    lr += __shfl_xor(lr, 32);
    float inv = 1.f / lr;
    int b = bh >> 3, h = bh & 7;
#pragma unroll
    for (int r = 0; r < 4; r++) {
        float invr = __shfl(inv, quad * 4 + r);
        size_t row = (size_t)(b * 2048 + ibase + quad * 4 + r);
        u16* o = out + row * 512 + h * 64 + l16;
        o[0]  = f2bf(O[0][r] * invr);
        o[16] = f2bf(O[1][r] * invr);
        o[32] = f2bf(O[2][r] * invr);
        o[48] = f2bf(O[3][r] * invr);
    }
}

// ---------------------------------------------------------------------------
extern "C" void kernel_launch(void* const* d_in, const int* in_sizes, int n_in,
                              void* d_out, int out_size, void* d_ws, size_t ws_size,
                              hipStream_t stream) {
    const float* x      = (const float*)d_in[0];
    const float* sa_w   = (const float*)d_in[1];
    const float* sa_b   = (const float*)d_in[2];
    const float* ca_w   = (const float*)d_in[3];
    const float* ca_b   = (const float*)d_in[4];
    const float* ffn_w  = (const float*)d_in[5];
    const float* ffn_b  = (const float*)d_in[6];
    const float* a1_wq  = (const float*)d_in[7];
    const float* a1_bq  = (const float*)d_in[8];
    const float* a1_wv  = (const float*)d_in[9];
    const float* a1_bv  = (const float*)d_in[10];
    const float* a1_wo  = (const float*)d_in[11];
    const float* a1_bo  = (const float*)d_in[12];
    const float* a2_wq  = (const float*)d_in[13];
    const float* a2_bq  = (const float*)d_in[14];
    const float* a2_wv  = (const float*)d_in[15];
    const float* a2_bv  = (const float*)d_in[16];
    const float* a2_wo  = (const float*)d_in[17];
    const float* a2_bo  = (const float*)d_in[18];
    const float* ff_w1  = (const float*)d_in[19];
    const float* ff_b1  = (const float*)d_in[20];
    const float* ff_w2  = (const float*)d_in[21];
    const float* ff_b2  = (const float*)d_in[22];

    char* ws = (char*)d_ws;
    const size_t MB = 1ull << 20;
    float* x_res   = (float*)(ws);              // 16 MB fp32 residual stream
    u16* xn        = (u16*)(ws + 16 * MB);      // 8 MB normed activations (bf16)
    u16* wT_a1qv   = (u16*)(ws + 24 * MB);      // 1 MB [1024][512] (wq^T | wv^T)
    u16* wT_a2qv   = (u16*)(ws + 25 * MB);      // 1 MB
    u16* wT_a1o    = (u16*)(ws + 26 * MB);      // 0.5 MB
    u16* wT_a2o    = (u16*)(ws + 26 * MB + 512 * 1024);
    u16* wT_ff1    = (u16*)(ws + 27 * MB);      // 4 MB [4096][512]
    u16* wT_ff2    = (u16*)(ws + 31 * MB);      // 2 MB [512][2048]
    u16* qbuf      = (u16*)(ws + 34 * MB);      // 8 MB [bh][2048][64]
    u16* vtp       = (u16*)(ws + 42 * MB);      // 8 MB [bh][64][2048] (j-permuted)
    float* aab     = (float*)(ws + 50 * MB);    // 256 KB (0.125*||q||^2)
    u16* attn_o    = (u16*)(ws + 51 * MB);      // 8 MB bf16 [8192][512]
    u16* gbuf      = (u16*)(ws + 60 * MB);      // 32 MB [8192][2048] bf16

    (void)in_sizes; (void)n_in; (void)out_size; (void)ws_size;

    // weight transposes (fp32 -> bf16 [N][K]); q|v concatenated
    transpose_f32_bf16<<<dim3(16, 16), 256, 0, stream>>>(a1_wq, wT_a1qv, 512, 512);
    transpose_f32_bf16<<<dim3(16, 16), 256, 0, stream>>>(a1_wv, wT_a1qv + 512 * 512, 512, 512);
    transpose_f32_bf16<<<dim3(16, 16), 256, 0, stream>>>(a2_wq, wT_a2qv, 512, 512);
    transpose_f32_bf16<<<dim3(16, 16), 256, 0, stream>>>(a2_wv, wT_a2qv + 512 * 512, 512, 512);
    transpose_f32_bf16<<<dim3(16, 16), 256, 0, stream>>>(a1_wo, wT_a1o, 512, 512);
    transpose_f32_bf16<<<dim3(16, 16), 256, 0, stream>>>(a2_wo, wT_a2o, 512, 512);
    transpose_f32_bf16<<<dim3(128, 16), 256, 0, stream>>>(ff_w1, wT_ff1, 512, 4096);
    transpose_f32_bf16<<<dim3(16, 64), 256, 0, stream>>>(ff_w2, wT_ff2, 2048, 512);

    // === attention 1 (self) ===
    ln_kernel<<<8192, 256, 0, stream>>>(x, sa_w, sa_b, xn);
    gemm_rect<4><<<dim3(64, 16), 256, 0, stream>>>(xn, wT_a1qv, a1_bq, a1_bv, nullptr, nullptr, qbuf, vtp, aab, 8192, 1024, 512);
    attn_mfma<<<dim3(32, 32), 256, 0, stream>>>(qbuf, vtp, aab, attn_o);
    gemm_rect<2><<<dim3(64, 8), 256, 0, stream>>>(attn_o, wT_a1o, a1_bo, nullptr, x, x_res, nullptr, nullptr, nullptr, 8192, 512, 512);

    // === attention 2 ("cross", k=q, v from x) ===
    ln_kernel<<<8192, 256, 0, stream>>>(x_res, ca_w, ca_b, xn);
    gemm_rect<4><<<dim3(64, 16), 256, 0, stream>>>(xn, wT_a2qv, a2_bq, a2_bv, nullptr, nullptr, qbuf, vtp, aab, 8192, 1024, 512);
    attn_mfma<<<dim3(32, 32), 256, 0, stream>>>(qbuf, vtp, aab, attn_o);
    gemm_rect<2><<<dim3(64, 8), 256, 0, stream>>>(attn_o, wT_a2o, a2_bo, nullptr, x_res, x_res, nullptr, nullptr, nullptr, 8192, 512, 512);

    // === GEGLU FFN (geglu fused into ff1) ===
    ln_kernel<<<8192, 256, 0, stream>>>(x_res, ffn_w, ffn_b, xn);
    gemm_ff1<<<dim3(64, 32), 256, 0, stream>>>(xn, wT_ff1, ff_b1, gbuf, 512);
    gemm_rect<2><<<dim3(64, 8), 256, 0, stream>>>(gbuf, wT_ff2, ff_b2, nullptr, x_res, (float*)d_out, nullptr, nullptr, nullptr, 8192, 512, 2048);
}

// Round 10
// 421.784 us; speedup vs baseline: 1.2580x; 1.0165x over previous
//
#include <hip/hip_runtime.h>
#include <hip/hip_bf16.h>

// ---------------------------------------------------------------------------
// BasicTransformerBlock (l2-attention x2 + GEGLU FFN), MI355X gfx950
// Round 10: round-9 + (1) ff1 gelu via tanh/sigmoid form (erf was ~1/3 of
// ff1), (2) attention XCD swizzle bh=id&31 so each head's q/vt stays in one
// XCD's L2 (FETCH 68MB -> ~22MB), (3) 8 weight transposes merged into one
// segment-decoded dispatch.
// ---------------------------------------------------------------------------

typedef short bf16x8 __attribute__((ext_vector_type(8)));
typedef float f32x4 __attribute__((ext_vector_type(4)));
typedef unsigned short u16;
typedef unsigned int u32;

__device__ __forceinline__ float bf2f(u16 u) {
    return __uint_as_float(((u32)u) << 16);
}
__device__ __forceinline__ u16 f2bf(float f) {
    u32 u = __float_as_uint(f);
    u32 rb = ((u >> 16) & 1u) + 0x7fffu;   // round-to-nearest-even
    return (u16)((u + rb) >> 16);
}
// tanh-form gelu: x * sigmoid(1.59577(x + 0.044715 x^3)); |err| <~1e-3.
__device__ __forceinline__ float gelu_fast(float x) {
    float y = 1.5957691216f * (x + 0.044715f * x * x * x);
    return x / (1.f + __expf(-y));
}
__device__ __forceinline__ void gl2lds16(const u16* g, u16* l) {
    __builtin_amdgcn_global_load_lds(
        (const __attribute__((address_space(1))) void*)(unsigned long long)(uintptr_t)g,
        (__attribute__((address_space(3))) void*)(unsigned long long)(uintptr_t)l,
        16, 0, 0);
}

// ---------------------------------------------------------------------------
// Merged weight transpose: 8 segments of fp32 [R][C] -> bf16 [C][R].
struct TArgs {
    const float* src[8];
    u16* dst[8];
    int R[8], C[8];
    int start[9];
};
__global__ __launch_bounds__(256) void transpose_multi(TArgs a) {
    __shared__ float tile[32][33];
    int bid = blockIdx.x;
    int s = 0;
    while (bid >= a.start[s + 1]) s++;
    int local = bid - a.start[s];
    int R = a.R[s], C = a.C[s];
    int tx = C >> 5;
    int bx = local % tx, by = local / tx;
    const float* in = a.src[s];
    u16* out = a.dst[s];
    int t = threadIdx.x;
    int c = t & 31, r0 = (t >> 5) * 4;
#pragma unroll
    for (int i = 0; i < 4; i++)
        tile[r0 + i][c] = in[(size_t)(by * 32 + r0 + i) * C + bx * 32 + c];
    __syncthreads();
#pragma unroll
    for (int i = 0; i < 4; i++)
        out[(size_t)(bx * 32 + r0 + i) * R + by * 32 + c] = f2bf(tile[c][r0 + i]);
}

// ---------------------------------------------------------------------------
// LayerNorm: x fp32 [rows][512] -> out bf16, one block per row
__global__ __launch_bounds__(256) void ln_kernel(const float* __restrict__ x,
                                                 const float* __restrict__ w,
                                                 const float* __restrict__ b,
                                                 u16* __restrict__ out) {
    int row = blockIdx.x, t = threadIdx.x;
    const float* xr = x + (size_t)row * 512;
    float2 v = *(const float2*)(xr + t * 2);
    float s1 = v.x + v.y;
    float s2 = v.x * v.x + v.y * v.y;
#pragma unroll
    for (int m = 1; m < 64; m <<= 1) {
        s1 += __shfl_xor(s1, m);
        s2 += __shfl_xor(s2, m);
    }
    __shared__ float r1[4], r2[4];
    int wave = t >> 6, lane = t & 63;
    if (lane == 0) { r1[wave] = s1; r2[wave] = s2; }
    __syncthreads();
    float tot1 = r1[0] + r1[1] + r1[2] + r1[3];
    float tot2 = r2[0] + r2[1] + r2[2] + r2[3];
    float mu = tot1 * (1.f / 512.f);
    float var = tot2 * (1.f / 512.f) - mu * mu;
    float rs = rsqrtf(var + 1e-5f);
    float2 wv = *(const float2*)(w + t * 2);
    float2 bv = *(const float2*)(b + t * 2);
    float o0 = (v.x - mu) * rs * wv.x + bv.x;
    float o1 = (v.y - mu) * rs * wv.y + bv.y;
    u32 pack = (u32)f2bf(o0) | ((u32)f2bf(o1) << 16);
    *(u32*)(out + (size_t)row * 512 + t * 2) = pack;
}

// ---------------------------------------------------------------------------
// ff1+GEGLU fused rect GEMM: A [8192][512] bf16, BT = ff1^T [4096][512].
// Epilogue: g = a * gelu(gate) -> gbuf [8192][2048] bf16.
__global__ __launch_bounds__(256) void gemm_ff1(const u16* __restrict__ A,
                                                const u16* __restrict__ BT,
                                                const float* __restrict__ bias,
                                                u16* __restrict__ gout,
                                                int K) {
    __shared__ u16 As[2][128 * 32];
    __shared__ u16 Bs[2][128 * 32];   // rows 0-63 = a-half, 64-127 = gate-half
    int t = threadIdx.x;
    int wave = t >> 6, lane = t & 63, quad = lane >> 4, l16 = lane & 15;
    int m0 = blockIdx.x * 128, n0 = blockIdx.y * 64;
    f32x4 aacc[2][4], gacc[2][4];
#pragma unroll
    for (int i = 0; i < 2; i++)
#pragma unroll
        for (int j = 0; j < 4; j++) {
            aacc[i][j] = (f32x4){0.f, 0.f, 0.f, 0.f};
            gacc[i][j] = (f32x4){0.f, 0.f, 0.f, 0.f};
        }
    const u16* Ag = A + (size_t)(m0 + wave * 32 + (lane >> 2)) * K + (lane & 3) * 8;
    int brow = (wave < 2) ? (n0 + wave * 32) : (2048 + n0 + (wave - 2) * 32);
    const u16* Bg = BT + (size_t)(brow + (lane >> 2)) * K + (lane & 3) * 8;
    int lo = wave * 32 * 32;
    const size_t rstep = (size_t)16 * K;
    gl2lds16(Ag, &As[0][lo]);
    gl2lds16(Ag + rstep, &As[0][lo + 16 * 32]);
    gl2lds16(Bg, &Bs[0][lo]);
    gl2lds16(Bg + rstep, &Bs[0][lo + 16 * 32]);
    int buf = 0;
    for (int k0 = 0; k0 < K; k0 += 32, buf ^= 1) {
        int kn = (k0 + 32 < K) ? (k0 + 32) : k0;
        int nb = buf ^ 1;
        asm volatile("s_waitcnt lgkmcnt(0)\n\ts_barrier" ::: "memory");
        gl2lds16(Ag + kn, &As[nb][lo]);
        gl2lds16(Ag + kn + rstep, &As[nb][lo + 16 * 32]);
        gl2lds16(Bg + kn, &Bs[nb][lo]);
        gl2lds16(Bg + kn + rstep, &Bs[nb][lo + 16 * 32]);
        asm volatile("s_waitcnt vmcnt(4)\n\ts_barrier" ::: "memory");
        bf16x8 a[2];
#pragma unroll
        for (int i = 0; i < 2; i++)
            a[i] = *(const bf16x8*)&As[buf][(wave * 32 + i * 16 + l16) * 32 + quad * 8];
#pragma unroll
        for (int j = 0; j < 4; j++) {
            bf16x8 ba = *(const bf16x8*)&Bs[buf][(j * 16 + l16) * 32 + quad * 8];
            bf16x8 bg = *(const bf16x8*)&Bs[buf][(64 + j * 16 + l16) * 32 + quad * 8];
#pragma unroll
            for (int i = 0; i < 2; i++) {
                aacc[i][j] = __builtin_amdgcn_mfma_f32_16x16x32_bf16(a[i], ba, aacc[i][j], 0, 0, 0);
                gacc[i][j] = __builtin_amdgcn_mfma_f32_16x16x32_bf16(a[i], bg, gacc[i][j], 0, 0, 0);
            }
        }
    }
    asm volatile("s_waitcnt vmcnt(0)" ::: "memory");   // drain DMA before endpgm
    int row_base = m0 + wave * 32 + quad * 4;
#pragma unroll
    for (int j = 0; j < 4; j++) {
        int col = n0 + j * 16 + l16;
        float ba = bias[col];
        float bg = bias[2048 + col];
#pragma unroll
        for (int i = 0; i < 2; i++) {
#pragma unroll
            for (int r = 0; r < 4; r++) {
                int row = row_base + i * 16 + r;
                float av = aacc[i][j][r] + ba;
                float gv = gacc[i][j][r] + bg;
                gout[(size_t)row * 2048 + col] = f2bf(av * gelu_fast(gv));
            }
        }
    }
}

// ---------------------------------------------------------------------------
// Rect 128x64 MFMA GEMM (double-buffered, vmcnt(3)).
// MODE 2: fp32 out = acc + res | 4: qv split:
//   col<512 (q): qbuf [(b*8+h)][n][64] + fused AA write (aa = 0.125*sum q^2)
//   col>=512 (v): vtp [(b*8+h)][64][2048] j-cols PERMUTED per aligned 32-block
template <int MODE>
__global__ __launch_bounds__(256) void gemm_rect(const u16* __restrict__ A,
                                                 const u16* __restrict__ BT,
                                                 const float* __restrict__ bias,
                                                 const float* __restrict__ bias2,
                                                 const float* __restrict__ res,
                                                 float* __restrict__ outf,
                                                 u16* __restrict__ outb,
                                                 u16* __restrict__ outb2,
                                                 float* __restrict__ aa,
                                                 int M, int N, int K) {
    __shared__ u16 As[2][128 * 32];
    __shared__ u16 Bs[2][64 * 32];
    int t = threadIdx.x;
    int wave = t >> 6, lane = t & 63, quad = lane >> 4, l16 = lane & 15;
    int m0 = blockIdx.x * 128, n0 = blockIdx.y * 64;
    f32x4 acc[2][4];
#pragma unroll
    for (int i = 0; i < 2; i++)
#pragma unroll
        for (int j = 0; j < 4; j++) acc[i][j] = (f32x4){0.f, 0.f, 0.f, 0.f};
    const u16* Ag = A + (size_t)(m0 + wave * 32 + (lane >> 2)) * K + (lane & 3) * 8;
    const u16* Bg = BT + (size_t)(n0 + wave * 16 + (lane >> 2)) * K + (lane & 3) * 8;
    int loA = wave * 32 * 32;
    int loB = wave * 16 * 32;
    const size_t rstep = (size_t)16 * K;
    gl2lds16(Ag, &As[0][loA]);
    gl2lds16(Ag + rstep, &As[0][loA + 16 * 32]);
    gl2lds16(Bg, &Bs[0][loB]);
    int buf = 0;
    for (int k0 = 0; k0 < K; k0 += 32, buf ^= 1) {
        int kn = (k0 + 32 < K) ? (k0 + 32) : k0;
        int nb = buf ^ 1;
        asm volatile("s_waitcnt lgkmcnt(0)\n\ts_barrier" ::: "memory");
        gl2lds16(Ag + kn, &As[nb][loA]);
        gl2lds16(Ag + kn + rstep, &As[nb][loA + 16 * 32]);
        gl2lds16(Bg + kn, &Bs[nb][loB]);
        asm volatile("s_waitcnt vmcnt(3)\n\ts_barrier" ::: "memory");
        bf16x8 a[2], b[4];
#pragma unroll
        for (int i = 0; i < 2; i++)
            a[i] = *(const bf16x8*)&As[buf][(wave * 32 + i * 16 + l16) * 32 + quad * 8];
#pragma unroll
        for (int j = 0; j < 4; j++)
            b[j] = *(const bf16x8*)&Bs[buf][(j * 16 + l16) * 32 + quad * 8];
#pragma unroll
        for (int i = 0; i < 2; i++)
#pragma unroll
            for (int j = 0; j < 4; j++)
                acc[i][j] = __builtin_amdgcn_mfma_f32_16x16x32_bf16(a[i], b[j], acc[i][j], 0, 0, 0);
    }
    asm volatile("s_waitcnt vmcnt(0)" ::: "memory");   // drain DMA before endpgm
    int row_base = m0 + wave * 32 + quad * 4;
    float ssq[2][4];
#pragma unroll
    for (int i = 0; i < 2; i++)
#pragma unroll
        for (int r = 0; r < 4; r++) ssq[i][r] = 0.f;
#pragma unroll
    for (int j = 0; j < 4; j++) {
        int col = n0 + j * 16 + l16;
        float bv;
        if (MODE == 4) bv = (col < 512) ? bias[col] : bias2[col - 512];
        else bv = bias[col];
#pragma unroll
        for (int i = 0; i < 2; i++) {
            int rowA = row_base + i * 16;
            if (MODE == 4) {
                if (col < 512) {
                    int hh = col >> 6, d = col & 63;
#pragma unroll
                    for (int r = 0; r < 4; r++) {
                        int row = rowA + r;
                        float v = acc[i][j][r] + bv;
                        ssq[i][r] += v * v;
                        outb[((size_t)((row >> 11) * 8 + hh) * 2048 + (row & 2047)) * 64 + d] = f2bf(v);
                    }
                } else {
                    int c2 = col - 512;
                    int hh = c2 >> 6, d = c2 & 63;
                    int n = rowA & 2047;
                    int a4 = (n >> 2) & 7;
                    int ncol = (n & ~31) + ((a4 & 3) << 3) + ((a4 >> 2) << 2);
                    u32 plo = (u32)f2bf(acc[i][j][0] + bv) | ((u32)f2bf(acc[i][j][1] + bv) << 16);
                    u32 phi = (u32)f2bf(acc[i][j][2] + bv) | ((u32)f2bf(acc[i][j][3] + bv) << 16);
                    uint2 pk; pk.x = plo; pk.y = phi;
                    *(uint2*)&outb2[((size_t)((rowA >> 11) * 8 + hh) * 64 + d) * 2048 + ncol] = pk;
                }
            } else {
#pragma unroll
                for (int r = 0; r < 4; r++) {
                    size_t idx = (size_t)(rowA + r) * N + col;
                    outf[idx] = acc[i][j][r] + bv + res[idx];
                }
            }
        }
    }
    // fused AA for the q-half (block covers exactly one head's 64 d-cols)
    if (MODE == 4 && n0 < 512) {
        int hh = n0 >> 6;
#pragma unroll
        for (int i = 0; i < 2; i++) {
#pragma unroll
            for (int r = 0; r < 4; r++) {
                float s = ssq[i][r];
                s += __shfl_xor(s, 1); s += __shfl_xor(s, 2);
                s += __shfl_xor(s, 4); s += __shfl_xor(s, 8);
                if (l16 == 0) {
                    int row = row_base + i * 16 + r;
                    aa[(size_t)((row >> 11) * 8 + hh) * 2048 + (row & 2047)] = s * 0.125f;
                }
            }
        }
    }
}

// ---------------------------------------------------------------------------
// MFMA flash L2-attention, S^T formulation, NO P round-trip, XCD-swizzled.
// 1-D grid of 1024: bh = id & 31 (so xcd = id%8 = bh%8 keeps each head's
// q/vt resident in one XCD's L2), itile = id >> 5.
__global__ __launch_bounds__(256) void attn_mfma(const u16* __restrict__ qbuf,
                                                 const u16* __restrict__ vtp,
                                                 const float* __restrict__ aas,
                                                 u16* __restrict__ out) {
    __shared__ u16 Qj[64][72];
    __shared__ u16 VT[64][72];
    int bid = blockIdx.x;
    int bh = bid & 31;
    int itile = bid >> 5;
    const u16* qb = qbuf + (size_t)bh * 2048 * 64;
    const u16* vtb = vtp + (size_t)bh * 64 * 2048;
    const float* aab = aas + (size_t)bh * 2048;
    int t = threadIdx.x;
    int wave = t >> 6, lane = t & 63, quad = lane >> 4, l16 = lane & 15;
    int ibase = itile * 64 + wave * 16;
    bf16x8 qf0 = *(const bf16x8*)(qb + (size_t)(ibase + l16) * 64 + quad * 8);
    bf16x8 qf1 = *(const bf16x8*)(qb + (size_t)(ibase + l16) * 64 + 32 + quad * 8);
    float ci = aab[ibase + l16];
    f32x4 O[4];
#pragma unroll
    for (int nt = 0; nt < 4; nt++) O[nt] = (f32x4){0.f, 0.f, 0.f, 0.f};
    float lr = 0.f;
    int sr = t >> 2, sc = (t & 3) * 16;
    uint4 nq0, nq1, nv0, nv1;
    {
        const u16* srcq = qb + (size_t)sr * 64 + sc;
        nq0 = *(const uint4*)srcq;
        nq1 = *(const uint4*)(srcq + 8);
        const u16* srcv = vtb + (size_t)sr * 2048 + sc;
        nv0 = *(const uint4*)srcv;
        nv1 = *(const uint4*)(srcv + 8);
    }
    for (int j0 = 0; j0 < 2048; j0 += 64) {
        __syncthreads();
        *(uint4*)&Qj[sr][sc] = nq0;
        *(uint4*)&Qj[sr][sc + 8] = nq1;
        *(uint4*)&VT[sr][sc] = nv0;
        *(uint4*)&VT[sr][sc + 8] = nv1;
        if (j0 + 64 < 2048) {
            const u16* srcq = qb + (size_t)(j0 + 64 + sr) * 64 + sc;
            nq0 = *(const uint4*)srcq;
            nq1 = *(const uint4*)(srcq + 8);
            const u16* srcv = vtb + (size_t)sr * 2048 + (j0 + 64) + sc;
            nv0 = *(const uint4*)srcv;
            nv1 = *(const uint4*)(srcv + 8);
        }
        __syncthreads();
#pragma unroll
        for (int c = 0; c < 2; c++) {
            int j1 = c * 32, j2 = c * 32 + 16;
            bf16x8 a10 = *(const bf16x8*)&Qj[j1 + l16][quad * 8];
            bf16x8 a11 = *(const bf16x8*)&Qj[j1 + l16][32 + quad * 8];
            f32x4 s0 = {0.f, 0.f, 0.f, 0.f};
            s0 = __builtin_amdgcn_mfma_f32_16x16x32_bf16(a10, qf0, s0, 0, 0, 0);
            s0 = __builtin_amdgcn_mfma_f32_16x16x32_bf16(a11, qf1, s0, 0, 0, 0);
            bf16x8 a20 = *(const bf16x8*)&Qj[j2 + l16][quad * 8];
            bf16x8 a21 = *(const bf16x8*)&Qj[j2 + l16][32 + quad * 8];
            f32x4 s1 = {0.f, 0.f, 0.f, 0.f};
            s1 = __builtin_amdgcn_mfma_f32_16x16x32_bf16(a20, qf0, s1, 0, 0, 0);
            s1 = __builtin_amdgcn_mfma_f32_16x16x32_bf16(a21, qf1, s1, 0, 0, 0);
            float4 aav0 = *(const float4*)(aab + j0 + j1 + quad * 4);
            float4 aav1 = *(const float4*)(aab + j0 + j2 + quad * 4);
            float p0 = __expf(s0[0] * 0.25f - aav0.x - ci);
            float p1 = __expf(s0[1] * 0.25f - aav0.y - ci);
            float p2 = __expf(s0[2] * 0.25f - aav0.z - ci);
            float p3 = __expf(s0[3] * 0.25f - aav0.w - ci);
            float p4 = __expf(s1[0] * 0.25f - aav1.x - ci);
            float p5 = __expf(s1[1] * 0.25f - aav1.y - ci);
            float p6 = __expf(s1[2] * 0.25f - aav1.z - ci);
            float p7 = __expf(s1[3] * 0.25f - aav1.w - ci);
            lr += (p0 + p1 + p2 + p3) + (p4 + p5 + p6 + p7);
            bf16x8 pa;
            u32* pu = (u32*)&pa;
            pu[0] = __builtin_amdgcn_perm(__float_as_uint(p1), __float_as_uint(p0), 0x07060302u);
            pu[1] = __builtin_amdgcn_perm(__float_as_uint(p3), __float_as_uint(p2), 0x07060302u);
            pu[2] = __builtin_amdgcn_perm(__float_as_uint(p5), __float_as_uint(p4), 0x07060302u);
            pu[3] = __builtin_amdgcn_perm(__float_as_uint(p7), __float_as_uint(p6), 0x07060302u);
#pragma unroll
            for (int nt = 0; nt < 4; nt++) {
                bf16x8 vf = *(const bf16x8*)&VT[nt * 16 + l16][c * 32 + quad * 8];
                O[nt] = __builtin_amdgcn_mfma_f32_16x16x32_bf16(pa, vf, O[nt], 0, 0, 0);
            }
        }
    }
    lr += __shfl_xor(lr, 16);
    lr += __shfl_xor(lr, 32);
    float inv = 1.f / lr;
    int b = bh >> 3, h = bh & 7;
#pragma unroll
    for (int r = 0; r < 4; r++) {
        float invr = __shfl(inv, quad * 4 + r);
        size_t row = (size_t)(b * 2048 + ibase + quad * 4 + r);
        u16* o = out + row * 512 + h * 64 + l16;
        o[0]  = f2bf(O[0][r] * invr);
        o[16] = f2bf(O[1][r] * invr);
        o[32] = f2bf(O[2][r] * invr);
        o[48] = f2bf(O[3][r] * invr);
    }
}

// ---------------------------------------------------------------------------
extern "C" void kernel_launch(void* const* d_in, const int* in_sizes, int n_in,
                              void* d_out, int out_size, void* d_ws, size_t ws_size,
                              hipStream_t stream) {
    const float* x      = (const float*)d_in[0];
    const float* sa_w   = (const float*)d_in[1];
    const float* sa_b   = (const float*)d_in[2];
    const float* ca_w   = (const float*)d_in[3];
    const float* ca_b   = (const float*)d_in[4];
    const float* ffn_w  = (const float*)d_in[5];
    const float* ffn_b  = (const float*)d_in[6];
    const float* a1_wq  = (const float*)d_in[7];
    const float* a1_bq  = (const float*)d_in[8];
    const float* a1_wv  = (const float*)d_in[9];
    const float* a1_bv  = (const float*)d_in[10];
    const float* a1_wo  = (const float*)d_in[11];
    const float* a1_bo  = (const float*)d_in[12];
    const float* a2_wq  = (const float*)d_in[13];
    const float* a2_bq  = (const float*)d_in[14];
    const float* a2_wv  = (const float*)d_in[15];
    const float* a2_bv  = (const float*)d_in[16];
    const float* a2_wo  = (const float*)d_in[17];
    const float* a2_bo  = (const float*)d_in[18];
    const float* ff_w1  = (const float*)d_in[19];
    const float* ff_b1  = (const float*)d_in[20];
    const float* ff_w2  = (const float*)d_in[21];
    const float* ff_b2  = (const float*)d_in[22];

    char* ws = (char*)d_ws;
    const size_t MB = 1ull << 20;
    float* x_res   = (float*)(ws);              // 16 MB fp32 residual stream
    u16* xn        = (u16*)(ws + 16 * MB);      // 8 MB normed activations (bf16)
    u16* wT_a1qv   = (u16*)(ws + 24 * MB);      // 1 MB [1024][512] (wq^T | wv^T)
    u16* wT_a2qv   = (u16*)(ws + 25 * MB);      // 1 MB
    u16* wT_a1o    = (u16*)(ws + 26 * MB);      // 0.5 MB
    u16* wT_a2o    = (u16*)(ws + 26 * MB + 512 * 1024);
    u16* wT_ff1    = (u16*)(ws + 27 * MB);      // 4 MB [4096][512]
    u16* wT_ff2    = (u16*)(ws + 31 * MB);      // 2 MB [512][2048]
    u16* qbuf      = (u16*)(ws + 34 * MB);      // 8 MB [bh][2048][64]
    u16* vtp       = (u16*)(ws + 42 * MB);      // 8 MB [bh][64][2048] (j-permuted)
    float* aab     = (float*)(ws + 50 * MB);    // 256 KB (0.125*||q||^2)
    u16* attn_o    = (u16*)(ws + 51 * MB);      // 8 MB bf16 [8192][512]
    u16* gbuf      = (u16*)(ws + 60 * MB);      // 32 MB [8192][2048] bf16

    (void)in_sizes; (void)n_in; (void)out_size; (void)ws_size;

    // merged weight transposes (fp32 -> bf16 [N][K]); q|v concatenated
    TArgs ta;
    ta.src[0] = a1_wq; ta.dst[0] = wT_a1qv;               ta.R[0] = 512;  ta.C[0] = 512;
    ta.src[1] = a1_wv; ta.dst[1] = wT_a1qv + 512 * 512;   ta.R[1] = 512;  ta.C[1] = 512;
    ta.src[2] = a2_wq; ta.dst[2] = wT_a2qv;               ta.R[2] = 512;  ta.C[2] = 512;
    ta.src[3] = a2_wv; ta.dst[3] = wT_a2qv + 512 * 512;   ta.R[3] = 512;  ta.C[3] = 512;
    ta.src[4] = a1_wo; ta.dst[4] = wT_a1o;                ta.R[4] = 512;  ta.C[4] = 512;
    ta.src[5] = a2_wo; ta.dst[5] = wT_a2o;                ta.R[5] = 512;  ta.C[5] = 512;
    ta.src[6] = ff_w1; ta.dst[6] = wT_ff1;                ta.R[6] = 512;  ta.C[6] = 4096;
    ta.src[7] = ff_w2; ta.dst[7] = wT_ff2;                ta.R[7] = 2048; ta.C[7] = 512;
    ta.start[0] = 0;
    for (int s = 0; s < 8; s++)
        ta.start[s + 1] = ta.start[s] + (ta.C[s] >> 5) * (ta.R[s] >> 5);
    transpose_multi<<<ta.start[8], 256, 0, stream>>>(ta);

    // === attention 1 (self) ===
    ln_kernel<<<8192, 256, 0, stream>>>(x, sa_w, sa_b, xn);
    gemm_rect<4><<<dim3(64, 16), 256, 0, stream>>>(xn, wT_a1qv, a1_bq, a1_bv, nullptr, nullptr, qbuf, vtp, aab, 8192, 1024, 512);
    attn_mfma<<<1024, 256, 0, stream>>>(qbuf, vtp, aab, attn_o);
    gemm_rect<2><<<dim3(64, 8), 256, 0, stream>>>(attn_o, wT_a1o, a1_bo, nullptr, x, x_res, nullptr, nullptr, nullptr, 8192, 512, 512);

    // === attention 2 ("cross", k=q, v from x) ===
    ln_kernel<<<8192, 256, 0, stream>>>(x_res, ca_w, ca_b, xn);
    gemm_rect<4><<<dim3(64, 16), 256, 0, stream>>>(xn, wT_a2qv, a2_bq, a2_bv, nullptr, nullptr, qbuf, vtp, aab, 8192, 1024, 512);
    attn_mfma<<<1024, 256, 0, stream>>>(qbuf, vtp, aab, attn_o);
    gemm_rect<2><<<dim3(64, 8), 256, 0, stream>>>(attn_o, wT_a2o, a2_bo, nullptr, x_res, x_res, nullptr, nullptr, nullptr, 8192, 512, 512);

    // === GEGLU FFN (geglu fused into ff1) ===
    ln_kernel<<<8192, 256, 0, stream>>>(x_res, ffn_w, ffn_b, xn);
    gemm_ff1<<<dim3(64, 32), 256, 0, stream>>>(xn, wT_ff1, ff_b1, gbuf, 512);
    gemm_rect<2><<<dim3(64, 8), 256, 0, stream>>>(gbuf, wT_ff2, ff_b2, nullptr, x_res, (float*)d_out, nullptr, nullptr, nullptr, 8192, 512, 2048);
}